// Round 15
// baseline (659.793 us; speedup 1.0000x reference)
//
#include <hip/hip_runtime.h>
#include <hip/hip_fp16.h>
#include <hip/hip_bf16.h>
#include <math.h>

#define BB 2
#define SS 2048
#define HH 16
#define TOPK 512
#define ROWS (BB*SS)
#define KDIM 1024
#define KP 3072      // 3*KDIM (split-bf16 tripled K)
#define NSTR 384     // 256 qi | 64 ki | 4 w | 60 zero-pad

using bf16x8 = __attribute__((ext_vector_type(8))) short;
using f32x4  = __attribute__((ext_vector_type(4))) float;
typedef _Float16 f16x8 __attribute__((ext_vector_type(8)));
typedef unsigned int u32;

__device__ __forceinline__ void gload16(const void* g, void* l) {
  __builtin_amdgcn_global_load_lds(
      (const __attribute__((address_space(1))) u32*)g,
      (__attribute__((address_space(3))) u32*)l, 16, 0, 0);
}

__device__ __forceinline__ void split_bf16(float f, short& hi, short& lo) {
  __hip_bfloat16 h = __float2bfloat16(f);
  float fh = __bfloat162float(h);
  __hip_bfloat16 l = __float2bfloat16(f - fh);
  hi = *reinterpret_cast<short*>(&h);
  lo = *reinterpret_cast<short*>(&l);
}

__device__ __forceinline__ unsigned fkey(float f) {
  unsigned u = __float_as_uint(f);
  if ((u << 1) == 0u) u = 0u;             // canonicalize -0.0 -> +0.0
  return (u & 0x80000000u) ? ~u : (u | 0x80000000u);
}

__global__ void rope_tab_k(float* __restrict__ ct, float* __restrict__ st) {
  int idx = blockIdx.x * blockDim.x + threadIdx.x;
  if (idx >= SS * 32) return;
  int s = idx >> 5, j = idx & 31;
  float theta = 1.0f / powf(10000.0f, (float)(2 * j) / 64.0f);
  float ang = (float)s * theta;
  float sv, cv;
  sincosf(ang, &sv, &cv);
  ct[idx] = cv;
  st[idx] = sv;
}

// X[M][1024] fp32 -> A[M][3072] bf16 triplets (hi,hi,lo)
__global__ __launch_bounds__(256) void pack_a_k(
    const float* __restrict__ X, short* __restrict__ A, int total4)
{
  int idx = blockIdx.x * 256 + threadIdx.x;
  if (idx >= total4) return;
  float4 v = ((const float4*)X)[idx];
  float a4[4] = {v.x, v.y, v.z, v.w};
  short o[12];
#pragma unroll
  for (int j = 0; j < 4; ++j) {
    short hs, ls; split_bf16(a4[j], hs, ls);
    o[3*j] = hs; o[3*j+1] = hs; o[3*j+2] = ls;
  }
  short* op = A + (size_t)idx * 12;
  *(short4*)(op)     = *(short4*)&o[0];
  *(short4*)(op + 4) = *(short4*)&o[4];
  *(short4*)(op + 8) = *(short4*)&o[8];
}

// W[K=1024][Nw] fp32 -> BT rows [n][3072] bf16 triplets (hi,lo,hi)
__global__ __launch_bounds__(256) void pack_bt_k(
    const float* __restrict__ W, short* __restrict__ BT, int Nw)
{
  __shared__ float tile[32][33];
  int kb = blockIdx.y * 32, nb = blockIdx.x * 32;
  int tx = threadIdx.x & 31, ty = threadIdx.x >> 5;
  for (int yy = ty; yy < 32; yy += 8) {
    float v = 0.f;
    if (nb + tx < Nw) v = W[(size_t)(kb + yy) * Nw + nb + tx];
    tile[yy][tx] = v;
  }
  __syncthreads();
  for (int yy = ty; yy < 32; yy += 8) {
    int n = nb + yy;
    if (n >= Nw) continue;
    int k = kb + tx;
    float f = tile[tx][yy];
    short hs, ls; split_bf16(f, hs, ls);
    short* orow = BT + (size_t)n * KP + 3 * k;
    orow[0] = hs; orow[1] = ls; orow[2] = hs;
  }
}

// Wcat[k][0:256]=Wq, [256:320]=Wk, [320:324]=Ww, [324:384]=0
__global__ __launch_bounds__(256) void pack_wcat_k(
    const float* __restrict__ Wq, const float* __restrict__ Wk,
    const float* __restrict__ Ww, float* __restrict__ Wcat)
{
  int idx = blockIdx.x * 256 + threadIdx.x;
  if (idx >= 1024 * NSTR) return;
  int k = idx / NSTR, n = idx - k * NSTR;
  float v = 0.f;
  if (n < 256)      v = Wq[(size_t)k * 256 + n];
  else if (n < 320) v = Wk[(size_t)k * 64 + (n - 256)];
  else if (n < 324) v = Ww[(size_t)k * 4 + (n - 320)];
  Wcat[idx] = v;
}

// bf16 MFMA GEMM, split-K over blockIdx.z: partial_z[M][N] (fp16) =
// A[M][kBeg:kBeg+kLen] * BT[N][kBeg:kBeg+kLen]^T. 128x128 tile, BK=64, 4 waves.
__global__ __launch_bounds__(256) void gemm_bf16h(
    const short* __restrict__ A, const short* __restrict__ BT,
    __half* __restrict__ C, int M, int N, int Kp, int kLen)
{
  __shared__ short As[128 * 64];
  __shared__ short Bs[128 * 64];
  const int tid = threadIdx.x;
  const int lane = tid & 63;
  const int wv = tid >> 6;
  const int m0 = blockIdx.y * 128, n0 = blockIdx.x * 128;
  const int z = blockIdx.z;
  const int kBeg = z * kLen;
  __half* Cp = C + (size_t)z * M * N;
  const int wr = (wv >> 1) * 64, wc = (wv & 1) * 64;
  f32x4 acc[4][4];
#pragma unroll
  for (int i = 0; i < 4; ++i)
#pragma unroll
    for (int j = 0; j < 4; ++j)
#pragma unroll
      for (int r = 0; r < 4; ++r) acc[i][j][r] = 0.0f;

  const int rsel = lane & 15;
  const int lrow = lane >> 3;          // 0..7
  const int lcol = (lane & 7) * 8;     // shorts
  for (int k0 = kBeg; k0 < kBeg + kLen; k0 += 64) {
#pragma unroll
    for (int q = 0; q < 4; ++q) {
      int c = wv * 4 + q;              // chunk 0..15 (8 rows each)
      int row = c * 8 + lrow;
      gload16(A  + (size_t)(m0 + row) * Kp + k0 + lcol, &As[c * 512]);
      gload16(BT + (size_t)(n0 + row) * Kp + k0 + lcol, &Bs[c * 512]);
    }
    __syncthreads();
#pragma unroll
    for (int kk = 0; kk < 2; ++kk) {
      bf16x8 af[4], bfr[4];
      int kof = kk * 32 + (lane >> 4) * 8;
#pragma unroll
      for (int i = 0; i < 4; ++i) {
        af[i]  = *(const bf16x8*)&As[(wr + i * 16 + rsel) * 64 + kof];
        bfr[i] = *(const bf16x8*)&Bs[(wc + i * 16 + rsel) * 64 + kof];
      }
#pragma unroll
      for (int i = 0; i < 4; ++i)
#pragma unroll
        for (int j = 0; j < 4; ++j)
          acc[i][j] = __builtin_amdgcn_mfma_f32_16x16x32_bf16(af[i], bfr[j], acc[i][j], 0, 0, 0);
    }
    __syncthreads();
  }
  const int er = m0 + wr + (lane >> 4) * 4;
  const int ec = n0 + wc + rsel;
#pragma unroll
  for (int i = 0; i < 4; ++i)
#pragma unroll
    for (int j = 0; j < 4; ++j)
#pragma unroll
      for (int r = 0; r < 4; ++r)
        Cp[(size_t)(er + i * 16 + r) * N + ec + j * 16] = __float2half_rn(acc[i][j][r]);
}

// fp32 indexer GEMM: C[M][384] = A[M][1024] * Wcat[1024][384].
// 32x64 tile, 128 threads, 4x4/thread, grid (6,128)=768 blocks.
__global__ __launch_bounds__(128) void gemm_idx_k(
    const float* __restrict__ A, const float* __restrict__ Bw, float* __restrict__ C)
{
  __shared__ float As[16][36];
  __shared__ float Bs[16][68];
  int n0 = blockIdx.x * 64, m0 = blockIdx.y * 32;
  int tid = threadIdx.x;
  int tr = tid >> 4;        // 0..7 -> rows tr*4..+3
  int tc = tid & 15;        // 0..15 -> cols tc*4..+3
  float acc[4][4];
#pragma unroll
  for (int i = 0; i < 4; ++i)
#pragma unroll
    for (int j = 0; j < 4; ++j) acc[i][j] = 0.f;

  for (int k0 = 0; k0 < 1024; k0 += 16) {
    {
      int lin = tid * 4;
      int row = lin >> 4, kk = lin & 15;
      float4 av = *(const float4*)(A + (size_t)(m0 + row) * 1024 + k0 + kk);
      As[kk + 0][row] = av.x; As[kk + 1][row] = av.y;
      As[kk + 2][row] = av.z; As[kk + 3][row] = av.w;
      int lin2 = tid * 8;
      int bk = lin2 >> 6, bc = lin2 & 63;
      const float* bp = Bw + (size_t)(k0 + bk) * NSTR + n0 + bc;
      *(float4*)&Bs[bk][bc]     = *(const float4*)(bp);
      *(float4*)&Bs[bk][bc + 4] = *(const float4*)(bp + 4);
    }
    __syncthreads();
#pragma unroll
    for (int k = 0; k < 16; ++k) {
      float a[4], b[4];
      *(float4*)&a[0] = *(const float4*)&As[k][tr * 4];
      *(float4*)&b[0] = *(const float4*)&Bs[k][tc * 4];
#pragma unroll
      for (int i = 0; i < 4; ++i)
#pragma unroll
        for (int j = 0; j < 4; ++j)
          acc[i][j] = fmaf(a[i], b[j], acc[i][j]);
    }
    __syncthreads();
  }
#pragma unroll
  for (int i = 0; i < 4; ++i)
    *(float4*)(C + (size_t)(m0 + tr * 4 + i) * NSTR + n0 + tc * 4) = *(float4*)&acc[i][0];
}

// P (2 fp16 partials, stride ROWS*3072) -> sum -> RoPE(q,k) + fp16; Q pre-scaled 1/8.
__global__ __launch_bounds__(256) void qkv_post_k(
    const __half* __restrict__ P, const float* __restrict__ ct, const float* __restrict__ st,
    __half* __restrict__ Qh, __half* __restrict__ Kh, __half* __restrict__ Vh)
{
  int idx = blockIdx.x * 256 + threadIdx.x;
  if (idx >= ROWS * 384) return;
  int m = idx / 384;
  int g = idx - m * 384;
  int col0 = g * 8;
  const __half* c0 = P + (size_t)m * 3072 + col0;
  const __half* c1 = c0 + (size_t)ROWS * 3072;
  float4 u = *(const float4*)c0;
  float4 v = *(const float4*)c1;
  const __half2* hu = (const __half2*)&u;
  const __half2* hv = (const __half2*)&v;
  float a[8];
#pragma unroll
  for (int c = 0; c < 4; ++c) {
    float2 x = __half22float2(hu[c]);
    float2 y = __half22float2(hv[c]);
    a[2*c]   = x.x + y.x;
    a[2*c+1] = x.y + y.y;
  }
  int sec = col0 >> 10;
  int cin = col0 & 1023;
  size_t orow = (size_t)m * 1024 + cin;
  if (sec == 2) {
    __half2 hh[4];
#pragma unroll
    for (int c = 0; c < 4; ++c) hh[c] = __floats2half2_rn(a[2*c], a[2*c+1]);
    *(float4*)(Vh + orow) = *(float4*)hh;
  } else {
    int t = m & (SS - 1);
    int jb = (cin & 63) >> 1;
    float o[8];
#pragma unroll
    for (int c = 0; c < 4; ++c) {
      float cv = ct[t * 32 + jb + c], sv = st[t * 32 + jb + c];
      float x1 = a[2*c], x2 = a[2*c+1];
      o[2*c]   = x1 * cv - x2 * sv;
      o[2*c+1] = x2 * cv + x1 * sv;
    }
    if (sec == 0) {
#pragma unroll
      for (int c = 0; c < 8; ++c) o[c] *= 0.125f;   // fold 1/sqrt(64)
    }
    __half2 hh[4];
#pragma unroll
    for (int c = 0; c < 4; ++c) hh[c] = __floats2half2_rn(o[2*c], o[2*c+1]);
    __half* dst = (sec == 0) ? Qh : Kh;
    *(float4*)(dst + orow) = *(float4*)hh;
  }
}

// Vh (b,s,h*64+d) -> VhT [(b*16+h)*64+d][s]
__global__ __launch_bounds__(256) void vt_k(
    const __half* __restrict__ Vh, __half* __restrict__ VhT)
{
  int st = blockIdx.x, bh = blockIdx.y;
  int b = bh >> 4, h = bh & 15;
  int s0 = st * 64;
  __shared__ __half tile[64][65];
  int tid = threadIdx.x;
#pragma unroll
  for (int rnd = 0; rnd < 2; ++rnd) {
    int row = (tid >> 3) + rnd * 32;
    int c8 = (tid & 7) * 8;
    *(float4*)&tile[row][c8] =
        *(const float4*)(Vh + ((size_t)b * SS + s0 + row) * 1024 + h * 64 + c8);
  }
  __syncthreads();
#pragma unroll
  for (int rnd = 0; rnd < 2; ++rnd) {
    int d = (tid >> 3) + rnd * 32;
    int s8 = (tid & 7) * 8;
    __half tmp[8];
#pragma unroll
    for (int j = 0; j < 8; ++j) tmp[j] = tile[s8 + j][d];
    *(float4*)(VhT + ((size_t)bh * 64 + d) * 2048 + s0 + s8) = *(float4*)tmp;
  }
}

// Per (b,t): indexer scores for s<=t (fp32, per-output chain identical to prior
// rounds), exact top-512 radix select (stable lowest-index ties), 2048-bit mask.
// Descending-t mapping (LPT) + 4-row score unroll with NAMED scalars (no arrays).
__global__ __launch_bounds__(256) void idx_topk_k(
    const float* __restrict__ Ccat, u32* __restrict__ msk)
{
  int b = blockIdx.y;
  int t = SS - 1 - blockIdx.x;      // longest blocks first
  int tid = threadIdx.x;
  int lane = tid & 63;
  int wv = tid >> 6;
  if (t < TOPK) {  // -1e9 ties => selection is exactly [0..511]
    if (tid < 64)
      msk[((size_t)b * SS + t) * 64 + tid] = (tid < 16) ? 0xFFFFFFFFu : 0u;
    return;
  }
  __shared__ u32 uk[SS];        // 8KB monotonic keys
  __shared__ u32 hist[256];
  __shared__ u32 w[64];
  __shared__ u32 s_bsel, s_above;

  if (tid < 64) w[tid] = 0u;

  const float4* qrow = (const float4*)(Ccat + ((size_t)b * SS + t) * NSTR);
  const float* wrow = Ccat + ((size_t)b * SS + t) * NSTR + 320;
  float w0 = wrow[0], w1 = wrow[1], w2 = wrow[2], w3 = wrow[3];

  // ---- scores -> keys: 4 rows/thread, named scalars, q amortized 4x ----
#pragma unroll 1
  for (int s0 = 0; s0 <= t; s0 += 1024) {
    int sA = s0 + tid;
    int sB = sA + 256, sC = sA + 512, sD = sA + 768;
    bool vA = (sA <= t), vB = (sB <= t), vC = (sC <= t), vD = (sD <= t);
    const float4* kA = (const float4*)(Ccat + ((size_t)b * SS + sA) * NSTR + 256);
    const float4* kB = (const float4*)(Ccat + ((size_t)b * SS + sB) * NSTR + 256);
    const float4* kC = (const float4*)(Ccat + ((size_t)b * SS + sC) * NSTR + 256);
    const float4* kD = (const float4*)(Ccat + ((size_t)b * SS + sD) * NSTR + 256);
    float aA0 = 0.f, aA1 = 0.f, aA2 = 0.f, aA3 = 0.f;
    float aB0 = 0.f, aB1 = 0.f, aB2 = 0.f, aB3 = 0.f;
    float aC0 = 0.f, aC1 = 0.f, aC2 = 0.f, aC3 = 0.f;
    float aD0 = 0.f, aD1 = 0.f, aD2 = 0.f, aD3 = 0.f;
#pragma unroll 4
    for (int d4 = 0; d4 < 16; ++d4) {
      float4 q0 = qrow[d4];
      float4 q1 = qrow[16 + d4];
      float4 q2 = qrow[32 + d4];
      float4 q3 = qrow[48 + d4];
      if (vA) {
        float4 kv = kA[d4];
        aA0 += q0.x * kv.x + q0.y * kv.y + q0.z * kv.z + q0.w * kv.w;
        aA1 += q1.x * kv.x + q1.y * kv.y + q1.z * kv.z + q1.w * kv.w;
        aA2 += q2.x * kv.x + q2.y * kv.y + q2.z * kv.z + q2.w * kv.w;
        aA3 += q3.x * kv.x + q3.y * kv.y + q3.z * kv.z + q3.w * kv.w;
      }
      if (vB) {
        float4 kv = kB[d4];
        aB0 += q0.x * kv.x + q0.y * kv.y + q0.z * kv.z + q0.w * kv.w;
        aB1 += q1.x * kv.x + q1.y * kv.y + q1.z * kv.z + q1.w * kv.w;
        aB2 += q2.x * kv.x + q2.y * kv.y + q2.z * kv.z + q2.w * kv.w;
        aB3 += q3.x * kv.x + q3.y * kv.y + q3.z * kv.z + q3.w * kv.w;
      }
      if (vC) {
        float4 kv = kC[d4];
        aC0 += q0.x * kv.x + q0.y * kv.y + q0.z * kv.z + q0.w * kv.w;
        aC1 += q1.x * kv.x + q1.y * kv.y + q1.z * kv.z + q1.w * kv.w;
        aC2 += q2.x * kv.x + q2.y * kv.y + q2.z * kv.z + q2.w * kv.w;
        aC3 += q3.x * kv.x + q3.y * kv.y + q3.z * kv.z + q3.w * kv.w;
      }
      if (vD) {
        float4 kv = kD[d4];
        aD0 += q0.x * kv.x + q0.y * kv.y + q0.z * kv.z + q0.w * kv.w;
        aD1 += q1.x * kv.x + q1.y * kv.y + q1.z * kv.z + q1.w * kv.w;
        aD2 += q2.x * kv.x + q2.y * kv.y + q2.z * kv.z + q2.w * kv.w;
        aD3 += q3.x * kv.x + q3.y * kv.y + q3.z * kv.z + q3.w * kv.w;
      }
    }
    if (vA) uk[sA] = fkey(fmaxf(aA0, 0.f) * w0 + fmaxf(aA1, 0.f) * w1 +
                          fmaxf(aA2, 0.f) * w2 + fmaxf(aA3, 0.f) * w3);
    if (vB) uk[sB] = fkey(fmaxf(aB0, 0.f) * w0 + fmaxf(aB1, 0.f) * w1 +
                          fmaxf(aB2, 0.f) * w2 + fmaxf(aB3, 0.f) * w3);
    if (vC) uk[sC] = fkey(fmaxf(aC0, 0.f) * w0 + fmaxf(aC1, 0.f) * w1 +
                          fmaxf(aC2, 0.f) * w2 + fmaxf(aC3, 0.f) * w3);
    if (vD) uk[sD] = fkey(fmaxf(aD0, 0.f) * w0 + fmaxf(aD1, 0.f) * w1 +
                          fmaxf(aD2, 0.f) * w2 + fmaxf(aD3, 0.f) * w3);
  }

  // ---- 4-pass radix: threshold key ----
  unsigned krem = TOPK;
  unsigned prefix = 0;
#pragma unroll 1
  for (int p = 0; p < 4; ++p) {
    int shift = 24 - 8 * p;
    u32 maskAbove = (p == 0) ? 0u : (0xFFFFFFFFu << (shift + 8));
    hist[tid] = 0u;
    __syncthreads();
#pragma unroll 1
    for (int s0 = 0; s0 <= t; s0 += 256) {
      int s = s0 + tid;
      if (s <= t) {
        u32 key = uk[s];
        if ((key & maskAbove) == prefix)
          atomicAdd(&hist[(key >> shift) & 255], 1u);
      }
    }
    __syncthreads();
    // wave-0 suffix scan of 256 bins (4 bins/lane), no inner barriers
    if (wv == 0) {
      uint4 hv = *(uint4*)&hist[lane * 4];
      u32 lsum = hv.x + hv.y + hv.z + hv.w;
      u32 x = lsum;
#pragma unroll
      for (int off = 1; off < 64; off <<= 1) {
        u32 y = __shfl_down(x, off);
        x += (lane + off < 64) ? y : 0u;
      }
      u32 esuf = x - lsum;            // suffix over lanes > L
      u32 S3 = esuf + hv.w;
      u32 S2 = S3 + hv.z;
      u32 S1 = S2 + hv.y;
      u32 S0 = S1 + hv.x;
      if (S0 >= krem && S1 < krem)  { s_bsel = lane * 4 + 0; s_above = S1; }
      if (S1 >= krem && S2 < krem)  { s_bsel = lane * 4 + 1; s_above = S2; }
      if (S2 >= krem && S3 < krem)  { s_bsel = lane * 4 + 2; s_above = S3; }
      if (S3 >= krem && esuf < krem){ s_bsel = lane * 4 + 3; s_above = esuf; }
    }
    __syncthreads();
    prefix |= (s_bsel << shift);
    krem -= s_above;
  }

  u32 Tkey = prefix;
  unsigned kfin = krem;               // # of ==Tkey to take (lowest indices)

  // ---- collect > Tkey: ballot word-OR straight into the bitmask ----
#pragma unroll 1
  for (int s0 = 0; s0 <= t; s0 += 256) {
    int s = s0 + tid;
    bool pred = (s <= t) && (uk[s] > Tkey);
    unsigned long long mba = __ballot(pred);
    int wbase = (s0 + wv * 64) >> 5;
    if (lane == 0 && (u32)mba) atomicOr(&w[wbase], (u32)mba);
    if (lane == 32 && (u32)(mba >> 32)) atomicOr(&w[wbase + 1], (u32)(mba >> 32));
  }
  // ---- collect == Tkey, lowest-index-first (wave 0) ----
  if (wv == 0) {
    unsigned taken = 0;
#pragma unroll 1
    for (int s0 = 0; s0 <= t && taken < kfin; s0 += 64) {
      int s = s0 + lane;
      bool pred = (s <= t) && (uk[s] == Tkey);
      unsigned long long mba = __ballot(pred);
      unsigned pre = (unsigned)__popcll(mba & ((1ull << lane) - 1ull));
      if (pred && (taken + pre) < kfin)
        atomicOr(&w[s >> 5], 1u << (s & 31));
      taken += (unsigned)__popcll(mba);
    }
  }
  __syncthreads();
  if (tid < 64) msk[((size_t)b * SS + t) * 64 + tid] = w[tid];
}

// Dense masked flash attention, f16 MFMA. Block = (b,h, 64-query tile).
// Emits split-bf16 triplets (hi,hi,lo) directly into Aattn for the out-proj GEMM.
__global__ __launch_bounds__(256) void attn_dense_k(
    const __half* __restrict__ Qh, const __half* __restrict__ Kh,
    const __half* __restrict__ VhT, const u32* __restrict__ msk,
    short* __restrict__ Aattn)
{
  int bid = blockIdx.x;
  int xcd = bid & 7, loc = bid >> 3;
  int bh = xcd * 4 + (loc >> 5);       // 4 (b,h) pairs per XCD -> K/V L2-resident
  int qt = loc & 31;
  int b = bh >> 4, h = bh & 15;
  int t0 = qt * 64;

  const int tid = threadIdx.x;
  const int lane = tid & 63;
  const int wv = tid >> 6;
  const int l15 = lane & 15;
  const int g = lane >> 4;

  __shared__ short lds[12800];          // Ks 4096 | Vt 4096 | Ps 4*1088 | mask 256
  short* Ks = lds;                      // [64 keys][8 chunks] XOR-swizzled
  short* Vt = lds + 4096;               // [64 dims][8 chunks] XOR-swizzled
  short* Ps = lds + 8192 + wv * 1088;   // per-wave [16 queries][68]
  u32* mlds = (u32*)(lds + 12544);      // [64 queries][2 words]

  const size_t brow = (size_t)b * SS;

  // Q A-fragments (m = this wave's 16 queries), resident in regs
  f16x8 qf0, qf1;
  {
    const __half* qp = Qh + (brow + t0 + wv * 16 + l15) * 1024 + h * 64 + g * 8;
    qf0 = *(const f16x8*)(qp);
    qf1 = *(const f16x8*)(qp + 32);
  }

  f32x4 accO[4];
#pragma unroll
  for (int n2 = 0; n2 < 4; ++n2)
#pragma unroll
    for (int r = 0; r < 4; ++r) accO[n2][r] = 0.f;
  float mRun[4] = {-1e30f, -1e30f, -1e30f, -1e30f};
  float sRun[4] = {0.f, 0.f, 0.f, 0.f};

  const int srow = lane >> 3;           // staging row within 8-row group
  const int scp  = (lane & 7) ^ srow;   // pre-swizzled source chunk

#pragma unroll 1
  for (int kt = 0; kt < 32; ++kt) {
    int kt0 = kt * 64;
    // ---- stage K tile, V^T tile (DMA, linear dest + inverse-swizzled src), mask ----
#pragma unroll
    for (int q = 0; q < 2; ++q) {
      int j = wv * 2 + q;
      gload16(Kh + (brow + kt0 + j * 8 + srow) * 1024 + h * 64 + scp * 8, Ks + j * 512);
      gload16(VhT + ((size_t)(bh * 64 + j * 8 + srow)) * 2048 + kt0 + scp * 8, Vt + j * 512);
    }
    if (tid < 128)
      mlds[tid] = msk[(brow + t0 + (tid >> 1)) * 64 + kt * 2 + (tid & 1)];
    __syncthreads();

    // ---- QK^T: D[m=query][n=key] ----
    f32x4 s4[4];
#pragma unroll
    for (int ns = 0; ns < 4; ++ns) {
#pragma unroll
      for (int r = 0; r < 4; ++r) s4[ns][r] = 0.f;
      int rowk = ns * 16 + l15;
      int cp0 = g ^ (rowk & 7);
      int cp1 = (4 + g) ^ (rowk & 7);
      f16x8 kf0 = *(const f16x8*)&Ks[rowk * 64 + cp0 * 8];
      f16x8 kf1 = *(const f16x8*)&Ks[rowk * 64 + cp1 * 8];
      s4[ns] = __builtin_amdgcn_mfma_f32_16x16x32_f16(qf0, kf0, s4[ns], 0, 0, 0);
      s4[ns] = __builtin_amdgcn_mfma_f32_16x16x32_f16(qf1, kf1, s4[ns], 0, 0, 0);
    }

    // ---- masked online softmax (per query row r; keys across l15 x ns) ----
#pragma unroll
    for (int r = 0; r < 4; ++r) {
      int qb2 = (wv * 16 + g * 4 + r) * 2;
      u32 w0 = mlds[qb2];
      u32 w1 = mlds[qb2 + 1];
      float le[4];
#pragma unroll
      for (int ns = 0; ns < 4; ++ns) {
        u32 w = (ns < 2) ? w0 : w1;
        int bit = (ns & 1) * 16 + l15;
        float l = s4[ns][r];
        le[ns] = ((w >> bit) & 1u) ? l : -1e30f;
      }
      float cm = fmaxf(fmaxf(le[0], le[1]), fmaxf(le[2], le[3]));
      cm = fmaxf(cm, __shfl_xor(cm, 1));
      cm = fmaxf(cm, __shfl_xor(cm, 2));
      cm = fmaxf(cm, __shfl_xor(cm, 4));
      cm = fmaxf(cm, __shfl_xor(cm, 8));
      float mn = fmaxf(mRun[r], cm);
      float fac = __expf(mRun[r] - mn);
      mRun[r] = mn;
      float sum = 0.f;
#pragma unroll
      for (int ns = 0; ns < 4; ++ns) {
        float ee = __expf(le[ns] - mn);
        ee = (le[ns] < -1e29f) ? 0.f : ee;   // masked -> exactly 0
        sum += ee;
        Ps[(g * 4 + r) * 68 + ns * 16 + l15] =
            (short)__half_as_ushort(__float2half_rn(ee));
      }
      sum += __shfl_xor(sum, 1);
      sum += __shfl_xor(sum, 2);
      sum += __shfl_xor(sum, 4);
      sum += __shfl_xor(sum, 8);
      sRun[r] = sRun[r] * fac + sum;
#pragma unroll
      for (int n2 = 0; n2 < 4; ++n2) accO[n2][r] *= fac;
    }

    // ---- PV: D[m=query][n=dim] += P * V ----
    f16x8 pa0, pa1;
    {
      const short* pp = &Ps[l15 * 68 + g * 8];
      float2 lo0 = *(const float2*)(pp);
      float2 hi0 = *(const float2*)(pp + 4);
      float2 lo1 = *(const float2*)(pp + 32);
      float2 hi1 = *(const float2*)(pp + 36);
      float4 c0 = make_float4(lo0.x, lo0.y, hi0.x, hi0.y);
      float4 c1 = make_float4(lo1.x, lo1.y, hi1.x, hi1.y);
      pa0 = *(const f16x8*)&c0;
      pa1 = *(const f16x8*)&c1;
    }
#pragma unroll
    for (int n2 = 0; n2 < 4; ++n2) {
      int rowd = n2 * 16 + l15;
      int cp0 = g ^ (rowd & 7);
      int cp1 = (4 + g) ^ (rowd & 7);
      f16x8 vf0 = *(const f16x8*)&Vt[rowd * 64 + cp0 * 8];
      f16x8 vf1 = *(const f16x8*)&Vt[rowd * 64 + cp1 * 8];
      accO[n2] = __builtin_amdgcn_mfma_f32_16x16x32_f16(pa0, vf0, accO[n2], 0, 0, 0);
      accO[n2] = __builtin_amdgcn_mfma_f32_16x16x32_f16(pa1, vf1, accO[n2], 0, 0, 0);
    }
    __syncthreads();
  }

#pragma unroll
  for (int r = 0; r < 4; ++r) {
    float inv = 1.0f / sRun[r];
    size_t grow = brow + t0 + wv * 16 + g * 4 + r;
    short* arow = Aattn + grow * 3072;
#pragma unroll
    for (int n2 = 0; n2 < 4; ++n2) {
      int col = h * 64 + n2 * 16 + l15;
      float v = accO[n2][r] * inv;
      short hs, ls; split_bf16(v, hs, ls);
      short* ap = arow + 3 * col;
      ap[0] = hs; ap[1] = hs; ap[2] = ls;
    }
  }
}

// out = sum of 3 fp16 out-proj partials (stride ROWS*1024)
__global__ __launch_bounds__(256) void redout_k(
    const __half* __restrict__ O, float* __restrict__ out)
{
  int idx = blockIdx.x * 256 + threadIdx.x;   // 8 elems/thread
  if (idx >= ROWS * 1024 / 8) return;
  const size_t PS = (size_t)ROWS * 1024;
  float4 u0 = *((const float4*)O + idx);
  float4 u1 = *((const float4*)(O + PS) + idx);
  float4 u2 = *((const float4*)(O + 2 * PS) + idx);
  const __half2* h0 = (const __half2*)&u0;
  const __half2* h1 = (const __half2*)&u1;
  const __half2* h2 = (const __half2*)&u2;
  float o[8];
#pragma unroll
  for (int c = 0; c < 4; ++c) {
    float2 a = __half22float2(h0[c]);
    float2 b = __half22float2(h1[c]);
    float2 d = __half22float2(h2[c]);
    o[2*c]   = a.x + b.x + d.x;
    o[2*c+1] = a.y + b.y + d.y;
  }
  float* op = out + (size_t)idx * 8;
  *(float4*)(op)     = make_float4(o[0], o[1], o[2], o[3]);
  *(float4*)(op + 4) = make_float4(o[4], o[5], o[6], o[7]);
}

extern "C" void kernel_launch(void* const* d_in, const int* in_sizes, int n_in,
                              void* d_out, int out_size, void* d_ws, size_t ws_size,
                              hipStream_t stream) {
  const float* x    = (const float*)d_in[0];
  const float* Wqkv = (const float*)d_in[1];
  const float* Wo   = (const float*)d_in[2];
  const float* Wq   = (const float*)d_in[3];
  const float* Wk   = (const float*)d_in[4];
  const float* Ww   = (const float*)d_in[5];
  float* out = (float*)d_out;

  float* fws = (float*)d_ws;
  size_t o = 0;
  __half* Qh    = (__half*)(fws + o);  o += (size_t)ROWS * 512;
  __half* Kh    = (__half*)(fws + o);  o += (size_t)ROWS * 512;
  __half* Vh    = (__half*)(fws + o);  o += (size_t)ROWS * 512;
  float*  ct    = fws + o;             o += (size_t)SS * 32;
  float*  st    = fws + o;             o += (size_t)SS * 32;
  float*  Ccat  = fws + o;             o += (size_t)ROWS * NSTR;       // fused qi|ki|w (padded)
  short*  BTwo  = (short*)(fws + o);   o += (size_t)1024 * KP / 2;
  short*  BTq   = (short*)(fws + o);   o += (size_t)3072 * KP / 2;
  short*  Ax    = (short*)(fws + o);                                   // aliased (ROWS*KP shorts):
  float*  Wcat  = fws + o + (size_t)ROWS * 1024;                       //  Wcat in dead tail of Ax
  /* region size */                    o += (size_t)ROWS * KP / 2;
  // Cbuf region (ROWS*3072 floats), time-multiplexed:
  //   phase 1: Ph = 2 fp16 qkv partials (2 x ROWS*3072 halves = whole region)
  //   phase 2 (post qkv_post): VhT (+8M fl), msk (+10.5M fl), Aattn ([0,6.3M fl))
  __half* Ph    = (__half*)(fws + o);
  short*  Aattn = (short*)(fws + o);
  __half* VhT   = (__half*)(fws + o + (size_t)8 * 1024 * 1024);
  u32*    msk   = (u32*)(fws + o + (size_t)10500 * 1024);
  o += (size_t)ROWS * 3072;
  // out-proj partials: 3 x ROWS*1024 halves == Qh+Kh+Vh region (dead by then)
  __half* Oparts = (__half*)Qh;

  rope_tab_k<<<dim3((SS * 32 + 255) / 256), dim3(256), 0, stream>>>(ct, st);

  // packs for the two MFMA GEMMs
  pack_a_k<<<dim3(ROWS * KDIM / 4 / 256), dim3(256), 0, stream>>>(x, Ax, ROWS * KDIM / 4);
  pack_bt_k<<<dim3(3072 / 32, 32), dim3(256), 0, stream>>>(Wqkv, BTq, 3072);
  pack_bt_k<<<dim3(1024 / 32, 32), dim3(256), 0, stream>>>(Wo, BTwo, 1024);

  // qkv GEMM (split-bf16 MFMA, split-K x2 -> fp16 partials)
  gemm_bf16h<<<dim3(3072 / 128, ROWS / 128, 2), dim3(256), 0, stream>>>(
      Ax, BTq, Ph, ROWS, 3072, KP, KP / 2);
  qkv_post_k<<<dim3((ROWS * 384 + 255) / 256), dim3(256), 0, stream>>>(Ph, ct, st, Qh, Kh, Vh);
  vt_k<<<dim3(SS / 64, BB * HH), dim3(256), 0, stream>>>(Vh, VhT);

  // fused indexer projections in fp32 (bit-identical chain; feeds exact top-k)
  pack_wcat_k<<<dim3((1024 * NSTR + 255) / 256), dim3(256), 0, stream>>>(Wq, Wk, Ww, Wcat);
  gemm_idx_k<<<dim3(NSTR / 64, ROWS / 32), dim3(128), 0, stream>>>(x, Wcat, Ccat);

  idx_topk_k<<<dim3(SS, BB), dim3(256), 0, stream>>>(Ccat, msk);
  attn_dense_k<<<dim3(1024), dim3(256), 0, stream>>>(Qh, Kh, VhT, msk, Aattn);

  // out = attn @ Wo (split-bf16 MFMA, split-K x3 -> fp16 partials in dead Qh/Kh/Vh)
  gemm_bf16h<<<dim3(1024 / 128, ROWS / 128, 3), dim3(256), 0, stream>>>(
      Aattn, BTwo, Oparts, ROWS, 1024, KP, KP / 3);
  redout_k<<<dim3(ROWS * 1024 / 8 / 256), dim3(256), 0, stream>>>(Oparts, out);
}

// Round 16
// 618.948 us; speedup vs baseline: 1.0660x; 1.0660x over previous
//
#include <hip/hip_runtime.h>
#include <hip/hip_fp16.h>
#include <hip/hip_bf16.h>
#include <math.h>

#define BB 2
#define SS 2048
#define HH 16
#define TOPK 512
#define ROWS (BB*SS)
#define KDIM 1024
#define KP 3072      // 3*KDIM (split-bf16 tripled K)
#define NSTR 384     // 256 qi | 64 ki | 4 w | 60 zero-pad

using bf16x8 = __attribute__((ext_vector_type(8))) short;
using f32x4  = __attribute__((ext_vector_type(4))) float;
typedef _Float16 f16x8 __attribute__((ext_vector_type(8)));
typedef unsigned int u32;

__device__ __forceinline__ void gload16(const void* g, void* l) {
  __builtin_amdgcn_global_load_lds(
      (const __attribute__((address_space(1))) u32*)g,
      (__attribute__((address_space(3))) u32*)l, 16, 0, 0);
}

__device__ __forceinline__ void split_bf16(float f, short& hi, short& lo) {
  __hip_bfloat16 h = __float2bfloat16(f);
  float fh = __bfloat162float(h);
  __hip_bfloat16 l = __float2bfloat16(f - fh);
  hi = *reinterpret_cast<short*>(&h);
  lo = *reinterpret_cast<short*>(&l);
}

__device__ __forceinline__ unsigned fkey(float f) {
  unsigned u = __float_as_uint(f);
  if ((u << 1) == 0u) u = 0u;             // canonicalize -0.0 -> +0.0
  return (u & 0x80000000u) ? ~u : (u | 0x80000000u);
}

__global__ void rope_tab_k(float* __restrict__ ct, float* __restrict__ st) {
  int idx = blockIdx.x * blockDim.x + threadIdx.x;
  if (idx >= SS * 32) return;
  int s = idx >> 5, j = idx & 31;
  float theta = 1.0f / powf(10000.0f, (float)(2 * j) / 64.0f);
  float ang = (float)s * theta;
  float sv, cv;
  sincosf(ang, &sv, &cv);
  ct[idx] = cv;
  st[idx] = sv;
}

// X[M][1024] fp32 -> A[M][3072] bf16 triplets (hi,hi,lo)
__global__ __launch_bounds__(256) void pack_a_k(
    const float* __restrict__ X, short* __restrict__ A, int total4)
{
  int idx = blockIdx.x * 256 + threadIdx.x;
  if (idx >= total4) return;
  float4 v = ((const float4*)X)[idx];
  float a4[4] = {v.x, v.y, v.z, v.w};
  short o[12];
#pragma unroll
  for (int j = 0; j < 4; ++j) {
    short hs, ls; split_bf16(a4[j], hs, ls);
    o[3*j] = hs; o[3*j+1] = hs; o[3*j+2] = ls;
  }
  short* op = A + (size_t)idx * 12;
  *(short4*)(op)     = *(short4*)&o[0];
  *(short4*)(op + 4) = *(short4*)&o[4];
  *(short4*)(op + 8) = *(short4*)&o[8];
}

// W[K=1024][Nw] fp32 -> BT rows [n][3072] bf16 triplets (hi,lo,hi)
__global__ __launch_bounds__(256) void pack_bt_k(
    const float* __restrict__ W, short* __restrict__ BT, int Nw)
{
  __shared__ float tile[32][33];
  int kb = blockIdx.y * 32, nb = blockIdx.x * 32;
  int tx = threadIdx.x & 31, ty = threadIdx.x >> 5;
  for (int yy = ty; yy < 32; yy += 8) {
    float v = 0.f;
    if (nb + tx < Nw) v = W[(size_t)(kb + yy) * Nw + nb + tx];
    tile[yy][tx] = v;
  }
  __syncthreads();
  for (int yy = ty; yy < 32; yy += 8) {
    int n = nb + yy;
    if (n >= Nw) continue;
    int k = kb + tx;
    float f = tile[tx][yy];
    short hs, ls; split_bf16(f, hs, ls);
    short* orow = BT + (size_t)n * KP + 3 * k;
    orow[0] = hs; orow[1] = ls; orow[2] = hs;
  }
}

// Wcat[k][0:256]=Wq, [256:320]=Wk, [320:324]=Ww, [324:384]=0
__global__ __launch_bounds__(256) void pack_wcat_k(
    const float* __restrict__ Wq, const float* __restrict__ Wk,
    const float* __restrict__ Ww, float* __restrict__ Wcat)
{
  int idx = blockIdx.x * 256 + threadIdx.x;
  if (idx >= 1024 * NSTR) return;
  int k = idx / NSTR, n = idx - k * NSTR;
  float v = 0.f;
  if (n < 256)      v = Wq[(size_t)k * 256 + n];
  else if (n < 320) v = Wk[(size_t)k * 64 + (n - 256)];
  else if (n < 324) v = Ww[(size_t)k * 4 + (n - 320)];
  Wcat[idx] = v;
}

// bf16 MFMA GEMM, split-K over blockIdx.z: partial_z[M][N] (fp16) =
// A[M][kBeg:kBeg+kLen] * BT[N][kBeg:kBeg+kLen]^T. 128x128 tile, BK=64, 4 waves.
__global__ __launch_bounds__(256) void gemm_bf16h(
    const short* __restrict__ A, const short* __restrict__ BT,
    __half* __restrict__ C, int M, int N, int Kp, int kLen)
{
  __shared__ short As[128 * 64];
  __shared__ short Bs[128 * 64];
  const int tid = threadIdx.x;
  const int lane = tid & 63;
  const int wv = tid >> 6;
  const int m0 = blockIdx.y * 128, n0 = blockIdx.x * 128;
  const int z = blockIdx.z;
  const int kBeg = z * kLen;
  __half* Cp = C + (size_t)z * M * N;
  const int wr = (wv >> 1) * 64, wc = (wv & 1) * 64;
  f32x4 acc[4][4];
#pragma unroll
  for (int i = 0; i < 4; ++i)
#pragma unroll
    for (int j = 0; j < 4; ++j)
#pragma unroll
      for (int r = 0; r < 4; ++r) acc[i][j][r] = 0.0f;

  const int rsel = lane & 15;
  const int lrow = lane >> 3;          // 0..7
  const int lcol = (lane & 7) * 8;     // shorts
  for (int k0 = kBeg; k0 < kBeg + kLen; k0 += 64) {
#pragma unroll
    for (int q = 0; q < 4; ++q) {
      int c = wv * 4 + q;              // chunk 0..15 (8 rows each)
      int row = c * 8 + lrow;
      gload16(A  + (size_t)(m0 + row) * Kp + k0 + lcol, &As[c * 512]);
      gload16(BT + (size_t)(n0 + row) * Kp + k0 + lcol, &Bs[c * 512]);
    }
    __syncthreads();
#pragma unroll
    for (int kk = 0; kk < 2; ++kk) {
      bf16x8 af[4], bfr[4];
      int kof = kk * 32 + (lane >> 4) * 8;
#pragma unroll
      for (int i = 0; i < 4; ++i) {
        af[i]  = *(const bf16x8*)&As[(wr + i * 16 + rsel) * 64 + kof];
        bfr[i] = *(const bf16x8*)&Bs[(wc + i * 16 + rsel) * 64 + kof];
      }
#pragma unroll
      for (int i = 0; i < 4; ++i)
#pragma unroll
        for (int j = 0; j < 4; ++j)
          acc[i][j] = __builtin_amdgcn_mfma_f32_16x16x32_bf16(af[i], bfr[j], acc[i][j], 0, 0, 0);
    }
    __syncthreads();
  }
  const int er = m0 + wr + (lane >> 4) * 4;
  const int ec = n0 + wc + rsel;
#pragma unroll
  for (int i = 0; i < 4; ++i)
#pragma unroll
    for (int j = 0; j < 4; ++j)
#pragma unroll
      for (int r = 0; r < 4; ++r)
        Cp[(size_t)(er + i * 16 + r) * N + ec + j * 16] = __float2half_rn(acc[i][j][r]);
}

// fp32 indexer GEMM: C[M][384] = A[M][1024] * Wcat[1024][384].
// 32x64 tile, 128 threads, 4x4/thread, grid (6,128)=768 blocks.
__global__ __launch_bounds__(128) void gemm_idx_k(
    const float* __restrict__ A, const float* __restrict__ Bw, float* __restrict__ C)
{
  __shared__ float As[16][36];
  __shared__ float Bs[16][68];
  int n0 = blockIdx.x * 64, m0 = blockIdx.y * 32;
  int tid = threadIdx.x;
  int tr = tid >> 4;        // 0..7 -> rows tr*4..+3
  int tc = tid & 15;        // 0..15 -> cols tc*4..+3
  float acc[4][4];
#pragma unroll
  for (int i = 0; i < 4; ++i)
#pragma unroll
    for (int j = 0; j < 4; ++j) acc[i][j] = 0.f;

  for (int k0 = 0; k0 < 1024; k0 += 16) {
    {
      int lin = tid * 4;
      int row = lin >> 4, kk = lin & 15;
      float4 av = *(const float4*)(A + (size_t)(m0 + row) * 1024 + k0 + kk);
      As[kk + 0][row] = av.x; As[kk + 1][row] = av.y;
      As[kk + 2][row] = av.z; As[kk + 3][row] = av.w;
      int lin2 = tid * 8;
      int bk = lin2 >> 6, bc = lin2 & 63;
      const float* bp = Bw + (size_t)(k0 + bk) * NSTR + n0 + bc;
      *(float4*)&Bs[bk][bc]     = *(const float4*)(bp);
      *(float4*)&Bs[bk][bc + 4] = *(const float4*)(bp + 4);
    }
    __syncthreads();
#pragma unroll
    for (int k = 0; k < 16; ++k) {
      float a[4], b[4];
      *(float4*)&a[0] = *(const float4*)&As[k][tr * 4];
      *(float4*)&b[0] = *(const float4*)&Bs[k][tc * 4];
#pragma unroll
      for (int i = 0; i < 4; ++i)
#pragma unroll
        for (int j = 0; j < 4; ++j)
          acc[i][j] = fmaf(a[i], b[j], acc[i][j]);
    }
    __syncthreads();
  }
#pragma unroll
  for (int i = 0; i < 4; ++i)
    *(float4*)(C + (size_t)(m0 + tr * 4 + i) * NSTR + n0 + tc * 4) = *(float4*)&acc[i][0];
}

// P (2 fp16 partials, stride ROWS*3072) -> sum -> RoPE(q,k) + fp16; Q pre-scaled 1/8.
__global__ __launch_bounds__(256) void qkv_post_k(
    const __half* __restrict__ P, const float* __restrict__ ct, const float* __restrict__ st,
    __half* __restrict__ Qh, __half* __restrict__ Kh, __half* __restrict__ Vh)
{
  int idx = blockIdx.x * 256 + threadIdx.x;
  if (idx >= ROWS * 384) return;
  int m = idx / 384;
  int g = idx - m * 384;
  int col0 = g * 8;
  const __half* c0 = P + (size_t)m * 3072 + col0;
  const __half* c1 = c0 + (size_t)ROWS * 3072;
  float4 u = *(const float4*)c0;
  float4 v = *(const float4*)c1;
  const __half2* hu = (const __half2*)&u;
  const __half2* hv = (const __half2*)&v;
  float a[8];
#pragma unroll
  for (int c = 0; c < 4; ++c) {
    float2 x = __half22float2(hu[c]);
    float2 y = __half22float2(hv[c]);
    a[2*c]   = x.x + y.x;
    a[2*c+1] = x.y + y.y;
  }
  int sec = col0 >> 10;
  int cin = col0 & 1023;
  size_t orow = (size_t)m * 1024 + cin;
  if (sec == 2) {
    __half2 hh[4];
#pragma unroll
    for (int c = 0; c < 4; ++c) hh[c] = __floats2half2_rn(a[2*c], a[2*c+1]);
    *(float4*)(Vh + orow) = *(float4*)hh;
  } else {
    int t = m & (SS - 1);
    int jb = (cin & 63) >> 1;
    float o[8];
#pragma unroll
    for (int c = 0; c < 4; ++c) {
      float cv = ct[t * 32 + jb + c], sv = st[t * 32 + jb + c];
      float x1 = a[2*c], x2 = a[2*c+1];
      o[2*c]   = x1 * cv - x2 * sv;
      o[2*c+1] = x2 * cv + x1 * sv;
    }
    if (sec == 0) {
#pragma unroll
      for (int c = 0; c < 8; ++c) o[c] *= 0.125f;   // fold 1/sqrt(64)
    }
    __half2 hh[4];
#pragma unroll
    for (int c = 0; c < 4; ++c) hh[c] = __floats2half2_rn(o[2*c], o[2*c+1]);
    __half* dst = (sec == 0) ? Qh : Kh;
    *(float4*)(dst + orow) = *(float4*)hh;
  }
}

// Vh (b,s,h*64+d) -> VhT [(b*16+h)*64+d][s]
__global__ __launch_bounds__(256) void vt_k(
    const __half* __restrict__ Vh, __half* __restrict__ VhT)
{
  int st = blockIdx.x, bh = blockIdx.y;
  int b = bh >> 4, h = bh & 15;
  int s0 = st * 64;
  __shared__ __half tile[64][65];
  int tid = threadIdx.x;
#pragma unroll
  for (int rnd = 0; rnd < 2; ++rnd) {
    int row = (tid >> 3) + rnd * 32;
    int c8 = (tid & 7) * 8;
    *(float4*)&tile[row][c8] =
        *(const float4*)(Vh + ((size_t)b * SS + s0 + row) * 1024 + h * 64 + c8);
  }
  __syncthreads();
#pragma unroll
  for (int rnd = 0; rnd < 2; ++rnd) {
    int d = (tid >> 3) + rnd * 32;
    int s8 = (tid & 7) * 8;
    __half tmp[8];
#pragma unroll
    for (int j = 0; j < 8; ++j) tmp[j] = tile[s8 + j][d];
    *(float4*)(VhT + ((size_t)bh * 64 + d) * 2048 + s0 + s8) = *(float4*)tmp;
  }
}

// Per (b,t): indexer scores for s<=t (fp32, per-output chain identical to prior
// rounds), exact top-512 radix select (stable lowest-index ties), 2048-bit mask.
// R12 score loop (no unrolling) + LPT descending-t mapping + q staged in LDS.
__global__ __launch_bounds__(256) void idx_topk_k(
    const float* __restrict__ Ccat, u32* __restrict__ msk)
{
  int b = blockIdx.y;
  int t = SS - 1 - blockIdx.x;      // LPT: longest blocks dispatch first
  int tid = threadIdx.x;
  int lane = tid & 63;
  int wv = tid >> 6;
  if (t < TOPK) {  // -1e9 ties => selection is exactly [0..511]
    if (tid < 64)
      msk[((size_t)b * SS + t) * 64 + tid] = (tid < 16) ? 0xFFFFFFFFu : 0u;
    return;
  }
  __shared__ u32 uk[SS];        // 8KB monotonic keys
  __shared__ float4 qs[64];     // 1KB q row, staged once
  __shared__ u32 hist[256];
  __shared__ u32 w[64];
  __shared__ u32 s_bsel, s_above;

  if (tid < 64) w[tid] = 0u;
  if (tid >= 128 && tid < 192)
    qs[tid - 128] = ((const float4*)(Ccat + ((size_t)b * SS + t) * NSTR))[tid - 128];
  const float* wrow = Ccat + ((size_t)b * SS + t) * NSTR + 320;
  float w0 = wrow[0], w1 = wrow[1], w2 = wrow[2], w3 = wrow[3];
  __syncthreads();

  // ---- scores -> keys (R12 chain; q read from LDS, same values/expression) ----
#pragma unroll 1
  for (int s0 = 0; s0 <= t; s0 += 256) {
    int s = s0 + tid;
    if (s <= t) {
      const float4* kp = (const float4*)(Ccat + ((size_t)b * SS + s) * NSTR + 256);
      float a0 = 0.f, a1 = 0.f, a2 = 0.f, a3 = 0.f;
#pragma unroll
      for (int d4 = 0; d4 < 16; ++d4) {
        float4 kv = kp[d4];
        float4 q0 = qs[d4];
        float4 q1 = qs[16 + d4];
        float4 q2 = qs[32 + d4];
        float4 q3 = qs[48 + d4];
        a0 += q0.x * kv.x + q0.y * kv.y + q0.z * kv.z + q0.w * kv.w;
        a1 += q1.x * kv.x + q1.y * kv.y + q1.z * kv.z + q1.w * kv.w;
        a2 += q2.x * kv.x + q2.y * kv.y + q2.z * kv.z + q2.w * kv.w;
        a3 += q3.x * kv.x + q3.y * kv.y + q3.z * kv.z + q3.w * kv.w;
      }
      float v = fmaxf(a0, 0.f) * w0 + fmaxf(a1, 0.f) * w1 +
                fmaxf(a2, 0.f) * w2 + fmaxf(a3, 0.f) * w3;
      uk[s] = fkey(v);
    }
  }

  // ---- 4-pass radix: threshold key ----
  unsigned krem = TOPK;
  unsigned prefix = 0;
#pragma unroll 1
  for (int p = 0; p < 4; ++p) {
    int shift = 24 - 8 * p;
    u32 maskAbove = (p == 0) ? 0u : (0xFFFFFFFFu << (shift + 8));
    hist[tid] = 0u;
    __syncthreads();
#pragma unroll 1
    for (int s0 = 0; s0 <= t; s0 += 256) {
      int s = s0 + tid;
      if (s <= t) {
        u32 key = uk[s];
        if ((key & maskAbove) == prefix)
          atomicAdd(&hist[(key >> shift) & 255], 1u);
      }
    }
    __syncthreads();
    // wave-0 suffix scan of 256 bins (4 bins/lane), no inner barriers
    if (wv == 0) {
      uint4 hv = *(uint4*)&hist[lane * 4];
      u32 lsum = hv.x + hv.y + hv.z + hv.w;
      u32 x = lsum;
#pragma unroll
      for (int off = 1; off < 64; off <<= 1) {
        u32 y = __shfl_down(x, off);
        x += (lane + off < 64) ? y : 0u;
      }
      u32 esuf = x - lsum;            // suffix over lanes > L
      u32 S3 = esuf + hv.w;
      u32 S2 = S3 + hv.z;
      u32 S1 = S2 + hv.y;
      u32 S0 = S1 + hv.x;
      if (S0 >= krem && S1 < krem)  { s_bsel = lane * 4 + 0; s_above = S1; }
      if (S1 >= krem && S2 < krem)  { s_bsel = lane * 4 + 1; s_above = S2; }
      if (S2 >= krem && S3 < krem)  { s_bsel = lane * 4 + 2; s_above = S3; }
      if (S3 >= krem && esuf < krem){ s_bsel = lane * 4 + 3; s_above = esuf; }
    }
    __syncthreads();
    prefix |= (s_bsel << shift);
    krem -= s_above;
  }

  u32 Tkey = prefix;
  unsigned kfin = krem;               // # of ==Tkey to take (lowest indices)

  // ---- collect > Tkey: ballot word-OR straight into the bitmask ----
#pragma unroll 1
  for (int s0 = 0; s0 <= t; s0 += 256) {
    int s = s0 + tid;
    bool pred = (s <= t) && (uk[s] > Tkey);
    unsigned long long mba = __ballot(pred);
    int wbase = (s0 + wv * 64) >> 5;
    if (lane == 0 && (u32)mba) atomicOr(&w[wbase], (u32)mba);
    if (lane == 32 && (u32)(mba >> 32)) atomicOr(&w[wbase + 1], (u32)(mba >> 32));
  }
  // ---- collect == Tkey, lowest-index-first (wave 0) ----
  if (wv == 0) {
    unsigned taken = 0;
#pragma unroll 1
    for (int s0 = 0; s0 <= t && taken < kfin; s0 += 64) {
      int s = s0 + lane;
      bool pred = (s <= t) && (uk[s] == Tkey);
      unsigned long long mba = __ballot(pred);
      unsigned pre = (unsigned)__popcll(mba & ((1ull << lane) - 1ull));
      if (pred && (taken + pre) < kfin)
        atomicOr(&w[s >> 5], 1u << (s & 31));
      taken += (unsigned)__popcll(mba);
    }
  }
  __syncthreads();
  if (tid < 64) msk[((size_t)b * SS + t) * 64 + tid] = w[tid];
}

// Dense masked flash attention, f16 MFMA. Block = (b,h, 64-query tile).
// Emits split-bf16 triplets (hi,hi,lo) directly into Aattn for the out-proj GEMM.
__global__ __launch_bounds__(256) void attn_dense_k(
    const __half* __restrict__ Qh, const __half* __restrict__ Kh,
    const __half* __restrict__ VhT, const u32* __restrict__ msk,
    short* __restrict__ Aattn)
{
  int bid = blockIdx.x;
  int xcd = bid & 7, loc = bid >> 3;
  int bh = xcd * 4 + (loc >> 5);       // 4 (b,h) pairs per XCD -> K/V L2-resident
  int qt = loc & 31;
  int b = bh >> 4, h = bh & 15;
  int t0 = qt * 64;

  const int tid = threadIdx.x;
  const int lane = tid & 63;
  const int wv = tid >> 6;
  const int l15 = lane & 15;
  const int g = lane >> 4;

  __shared__ short lds[12800];          // Ks 4096 | Vt 4096 | Ps 4*1088 | mask 256
  short* Ks = lds;                      // [64 keys][8 chunks] XOR-swizzled
  short* Vt = lds + 4096;               // [64 dims][8 chunks] XOR-swizzled
  short* Ps = lds + 8192 + wv * 1088;   // per-wave [16 queries][68]
  u32* mlds = (u32*)(lds + 12544);      // [64 queries][2 words]

  const size_t brow = (size_t)b * SS;

  // Q A-fragments (m = this wave's 16 queries), resident in regs
  f16x8 qf0, qf1;
  {
    const __half* qp = Qh + (brow + t0 + wv * 16 + l15) * 1024 + h * 64 + g * 8;
    qf0 = *(const f16x8*)(qp);
    qf1 = *(const f16x8*)(qp + 32);
  }

  f32x4 accO[4];
#pragma unroll
  for (int n2 = 0; n2 < 4; ++n2)
#pragma unroll
    for (int r = 0; r < 4; ++r) accO[n2][r] = 0.f;
  float mRun[4] = {-1e30f, -1e30f, -1e30f, -1e30f};
  float sRun[4] = {0.f, 0.f, 0.f, 0.f};

  const int srow = lane >> 3;           // staging row within 8-row group
  const int scp  = (lane & 7) ^ srow;   // pre-swizzled source chunk

#pragma unroll 1
  for (int kt = 0; kt < 32; ++kt) {
    int kt0 = kt * 64;
    // ---- stage K tile, V^T tile (DMA, linear dest + inverse-swizzled src), mask ----
#pragma unroll
    for (int q = 0; q < 2; ++q) {
      int j = wv * 2 + q;
      gload16(Kh + (brow + kt0 + j * 8 + srow) * 1024 + h * 64 + scp * 8, Ks + j * 512);
      gload16(VhT + ((size_t)(bh * 64 + j * 8 + srow)) * 2048 + kt0 + scp * 8, Vt + j * 512);
    }
    if (tid < 128)
      mlds[tid] = msk[(brow + t0 + (tid >> 1)) * 64 + kt * 2 + (tid & 1)];
    __syncthreads();

    // ---- QK^T: D[m=query][n=key] ----
    f32x4 s4[4];
#pragma unroll
    for (int ns = 0; ns < 4; ++ns) {
#pragma unroll
      for (int r = 0; r < 4; ++r) s4[ns][r] = 0.f;
      int rowk = ns * 16 + l15;
      int cp0 = g ^ (rowk & 7);
      int cp1 = (4 + g) ^ (rowk & 7);
      f16x8 kf0 = *(const f16x8*)&Ks[rowk * 64 + cp0 * 8];
      f16x8 kf1 = *(const f16x8*)&Ks[rowk * 64 + cp1 * 8];
      s4[ns] = __builtin_amdgcn_mfma_f32_16x16x32_f16(qf0, kf0, s4[ns], 0, 0, 0);
      s4[ns] = __builtin_amdgcn_mfma_f32_16x16x32_f16(qf1, kf1, s4[ns], 0, 0, 0);
    }

    // ---- masked online softmax (per query row r; keys across l15 x ns) ----
#pragma unroll
    for (int r = 0; r < 4; ++r) {
      int qb2 = (wv * 16 + g * 4 + r) * 2;
      u32 w0 = mlds[qb2];
      u32 w1 = mlds[qb2 + 1];
      float le[4];
#pragma unroll
      for (int ns = 0; ns < 4; ++ns) {
        u32 w = (ns < 2) ? w0 : w1;
        int bit = (ns & 1) * 16 + l15;
        float l = s4[ns][r];
        le[ns] = ((w >> bit) & 1u) ? l : -1e30f;
      }
      float cm = fmaxf(fmaxf(le[0], le[1]), fmaxf(le[2], le[3]));
      cm = fmaxf(cm, __shfl_xor(cm, 1));
      cm = fmaxf(cm, __shfl_xor(cm, 2));
      cm = fmaxf(cm, __shfl_xor(cm, 4));
      cm = fmaxf(cm, __shfl_xor(cm, 8));
      float mn = fmaxf(mRun[r], cm);
      float fac = __expf(mRun[r] - mn);
      mRun[r] = mn;
      float sum = 0.f;
#pragma unroll
      for (int ns = 0; ns < 4; ++ns) {
        float ee = __expf(le[ns] - mn);
        ee = (le[ns] < -1e29f) ? 0.f : ee;   // masked -> exactly 0
        sum += ee;
        Ps[(g * 4 + r) * 68 + ns * 16 + l15] =
            (short)__half_as_ushort(__float2half_rn(ee));
      }
      sum += __shfl_xor(sum, 1);
      sum += __shfl_xor(sum, 2);
      sum += __shfl_xor(sum, 4);
      sum += __shfl_xor(sum, 8);
      sRun[r] = sRun[r] * fac + sum;
#pragma unroll
      for (int n2 = 0; n2 < 4; ++n2) accO[n2][r] *= fac;
    }

    // ---- PV: D[m=query][n=dim] += P * V ----
    f16x8 pa0, pa1;
    {
      const short* pp = &Ps[l15 * 68 + g * 8];
      float2 lo0 = *(const float2*)(pp);
      float2 hi0 = *(const float2*)(pp + 4);
      float2 lo1 = *(const float2*)(pp + 32);
      float2 hi1 = *(const float2*)(pp + 36);
      float4 c0 = make_float4(lo0.x, lo0.y, hi0.x, hi0.y);
      float4 c1 = make_float4(lo1.x, lo1.y, hi1.x, hi1.y);
      pa0 = *(const f16x8*)&c0;
      pa1 = *(const f16x8*)&c1;
    }
#pragma unroll
    for (int n2 = 0; n2 < 4; ++n2) {
      int rowd = n2 * 16 + l15;
      int cp0 = g ^ (rowd & 7);
      int cp1 = (4 + g) ^ (rowd & 7);
      f16x8 vf0 = *(const f16x8*)&Vt[rowd * 64 + cp0 * 8];
      f16x8 vf1 = *(const f16x8*)&Vt[rowd * 64 + cp1 * 8];
      accO[n2] = __builtin_amdgcn_mfma_f32_16x16x32_f16(pa0, vf0, accO[n2], 0, 0, 0);
      accO[n2] = __builtin_amdgcn_mfma_f32_16x16x32_f16(pa1, vf1, accO[n2], 0, 0, 0);
    }
    __syncthreads();
  }

#pragma unroll
  for (int r = 0; r < 4; ++r) {
    float inv = 1.0f / sRun[r];
    size_t grow = brow + t0 + wv * 16 + g * 4 + r;
    short* arow = Aattn + grow * 3072;
#pragma unroll
    for (int n2 = 0; n2 < 4; ++n2) {
      int col = h * 64 + n2 * 16 + l15;
      float v = accO[n2][r] * inv;
      short hs, ls; split_bf16(v, hs, ls);
      short* ap = arow + 3 * col;
      ap[0] = hs; ap[1] = hs; ap[2] = ls;
    }
  }
}

// out = sum of 3 fp16 out-proj partials (stride ROWS*1024)
__global__ __launch_bounds__(256) void redout_k(
    const __half* __restrict__ O, float* __restrict__ out)
{
  int idx = blockIdx.x * 256 + threadIdx.x;   // 8 elems/thread
  if (idx >= ROWS * 1024 / 8) return;
  const size_t PS = (size_t)ROWS * 1024;
  float4 u0 = *((const float4*)O + idx);
  float4 u1 = *((const float4*)(O + PS) + idx);
  float4 u2 = *((const float4*)(O + 2 * PS) + idx);
  const __half2* h0 = (const __half2*)&u0;
  const __half2* h1 = (const __half2*)&u1;
  const __half2* h2 = (const __half2*)&u2;
  float o[8];
#pragma unroll
  for (int c = 0; c < 4; ++c) {
    float2 a = __half22float2(h0[c]);
    float2 b = __half22float2(h1[c]);
    float2 d = __half22float2(h2[c]);
    o[2*c]   = a.x + b.x + d.x;
    o[2*c+1] = a.y + b.y + d.y;
  }
  float* op = out + (size_t)idx * 8;
  *(float4*)(op)     = make_float4(o[0], o[1], o[2], o[3]);
  *(float4*)(op + 4) = make_float4(o[4], o[5], o[6], o[7]);
}

extern "C" void kernel_launch(void* const* d_in, const int* in_sizes, int n_in,
                              void* d_out, int out_size, void* d_ws, size_t ws_size,
                              hipStream_t stream) {
  const float* x    = (const float*)d_in[0];
  const float* Wqkv = (const float*)d_in[1];
  const float* Wo   = (const float*)d_in[2];
  const float* Wq   = (const float*)d_in[3];
  const float* Wk   = (const float*)d_in[4];
  const float* Ww   = (const float*)d_in[5];
  float* out = (float*)d_out;

  float* fws = (float*)d_ws;
  size_t o = 0;
  __half* Qh    = (__half*)(fws + o);  o += (size_t)ROWS * 512;
  __half* Kh    = (__half*)(fws + o);  o += (size_t)ROWS * 512;
  __half* Vh    = (__half*)(fws + o);  o += (size_t)ROWS * 512;
  float*  ct    = fws + o;             o += (size_t)SS * 32;
  float*  st    = fws + o;             o += (size_t)SS * 32;
  float*  Ccat  = fws + o;             o += (size_t)ROWS * NSTR;       // fused qi|ki|w (padded)
  short*  BTwo  = (short*)(fws + o);   o += (size_t)1024 * KP / 2;
  short*  BTq   = (short*)(fws + o);   o += (size_t)3072 * KP / 2;
  short*  Ax    = (short*)(fws + o);                                   // aliased (ROWS*KP shorts):
  float*  Wcat  = fws + o + (size_t)ROWS * 1024;                       //  Wcat in dead tail of Ax
  /* region size */                    o += (size_t)ROWS * KP / 2;
  // Cbuf region (ROWS*3072 floats), time-multiplexed:
  //   phase 1: Ph = 2 fp16 qkv partials (2 x ROWS*3072 halves = whole region)
  //   phase 2 (post qkv_post): VhT (+8M fl), msk (+10.5M fl), Aattn ([0,6.3M fl))
  __half* Ph    = (__half*)(fws + o);
  short*  Aattn = (short*)(fws + o);
  __half* VhT   = (__half*)(fws + o + (size_t)8 * 1024 * 1024);
  u32*    msk   = (u32*)(fws + o + (size_t)10500 * 1024);
  o += (size_t)ROWS * 3072;
  // out-proj partials: 3 x ROWS*1024 halves == Qh+Kh+Vh region (dead by then)
  __half* Oparts = (__half*)Qh;

  rope_tab_k<<<dim3((SS * 32 + 255) / 256), dim3(256), 0, stream>>>(ct, st);

  // packs for the two MFMA GEMMs
  pack_a_k<<<dim3(ROWS * KDIM / 4 / 256), dim3(256), 0, stream>>>(x, Ax, ROWS * KDIM / 4);
  pack_bt_k<<<dim3(3072 / 32, 32), dim3(256), 0, stream>>>(Wqkv, BTq, 3072);
  pack_bt_k<<<dim3(1024 / 32, 32), dim3(256), 0, stream>>>(Wo, BTwo, 1024);

  // qkv GEMM (split-bf16 MFMA, split-K x2 -> fp16 partials)
  gemm_bf16h<<<dim3(3072 / 128, ROWS / 128, 2), dim3(256), 0, stream>>>(
      Ax, BTq, Ph, ROWS, 3072, KP, KP / 2);
  qkv_post_k<<<dim3((ROWS * 384 + 255) / 256), dim3(256), 0, stream>>>(Ph, ct, st, Qh, Kh, Vh);
  vt_k<<<dim3(SS / 64, BB * HH), dim3(256), 0, stream>>>(Vh, VhT);

  // fused indexer projections in fp32 (bit-identical chain; feeds exact top-k)
  pack_wcat_k<<<dim3((1024 * NSTR + 255) / 256), dim3(256), 0, stream>>>(Wq, Wk, Ww, Wcat);
  gemm_idx_k<<<dim3(NSTR / 64, ROWS / 32), dim3(128), 0, stream>>>(x, Wcat, Ccat);

  idx_topk_k<<<dim3(SS, BB), dim3(256), 0, stream>>>(Ccat, msk);
  attn_dense_k<<<dim3(1024), dim3(256), 0, stream>>>(Qh, Kh, VhT, msk, Aattn);

  // out = attn @ Wo (split-bf16 MFMA, split-K x3 -> fp16 partials in dead Qh/Kh/Vh)
  gemm_bf16h<<<dim3(1024 / 128, ROWS / 128, 3), dim3(256), 0, stream>>>(
      Aattn, BTwo, Oparts, ROWS, 1024, KP, KP / 3);
  redout_k<<<dim3(ROWS * 1024 / 8 / 256), dim3(256), 0, stream>>>(Oparts, out);
}

// Round 17
// 530.605 us; speedup vs baseline: 1.2435x; 1.1665x over previous
//
#include <hip/hip_runtime.h>
#include <hip/hip_fp16.h>
#include <hip/hip_bf16.h>
#include <math.h>

#define BB 2
#define SS 2048
#define HH 16
#define TOPK 512
#define ROWS (BB*SS)
#define KDIM 1024
#define KP 3072      // 3*KDIM (split-bf16 tripled K)
#define NSTR 384     // 256 qi | 64 ki | 4 w | 60 zero-pad

using bf16x8 = __attribute__((ext_vector_type(8))) short;
using f32x4  = __attribute__((ext_vector_type(4))) float;
typedef _Float16 f16x8 __attribute__((ext_vector_type(8)));
typedef unsigned int u32;

__device__ __forceinline__ void gload16(const void* g, void* l) {
  __builtin_amdgcn_global_load_lds(
      (const __attribute__((address_space(1))) u32*)g,
      (__attribute__((address_space(3))) u32*)l, 16, 0, 0);
}

__device__ __forceinline__ void split_bf16(float f, short& hi, short& lo) {
  __hip_bfloat16 h = __float2bfloat16(f);
  float fh = __bfloat162float(h);
  __hip_bfloat16 l = __float2bfloat16(f - fh);
  hi = *reinterpret_cast<short*>(&h);
  lo = *reinterpret_cast<short*>(&l);
}

__device__ __forceinline__ unsigned fkey(float f) {
  unsigned u = __float_as_uint(f);
  if ((u << 1) == 0u) u = 0u;             // canonicalize -0.0 -> +0.0
  return (u & 0x80000000u) ? ~u : (u | 0x80000000u);
}

__global__ void rope_tab_k(float* __restrict__ ct, float* __restrict__ st) {
  int idx = blockIdx.x * blockDim.x + threadIdx.x;
  if (idx >= SS * 32) return;
  int s = idx >> 5, j = idx & 31;
  float theta = 1.0f / powf(10000.0f, (float)(2 * j) / 64.0f);
  float ang = (float)s * theta;
  float sv, cv;
  sincosf(ang, &sv, &cv);
  ct[idx] = cv;
  st[idx] = sv;
}

// X[M][1024] fp32 -> A[M][3072] bf16 triplets (hi,hi,lo)
__global__ __launch_bounds__(256) void pack_a_k(
    const float* __restrict__ X, short* __restrict__ A, int total4)
{
  int idx = blockIdx.x * 256 + threadIdx.x;
  if (idx >= total4) return;
  float4 v = ((const float4*)X)[idx];
  float a4[4] = {v.x, v.y, v.z, v.w};
  short o[12];
#pragma unroll
  for (int j = 0; j < 4; ++j) {
    short hs, ls; split_bf16(a4[j], hs, ls);
    o[3*j] = hs; o[3*j+1] = hs; o[3*j+2] = ls;
  }
  short* op = A + (size_t)idx * 12;
  *(short4*)(op)     = *(short4*)&o[0];
  *(short4*)(op + 4) = *(short4*)&o[4];
  *(short4*)(op + 8) = *(short4*)&o[8];
}

// W[K=1024][Nw] fp32 -> BT rows [n][3072] bf16 triplets (hi,lo,hi)
__global__ __launch_bounds__(256) void pack_bt_k(
    const float* __restrict__ W, short* __restrict__ BT, int Nw)
{
  __shared__ float tile[32][33];
  int kb = blockIdx.y * 32, nb = blockIdx.x * 32;
  int tx = threadIdx.x & 31, ty = threadIdx.x >> 5;
  for (int yy = ty; yy < 32; yy += 8) {
    float v = 0.f;
    if (nb + tx < Nw) v = W[(size_t)(kb + yy) * Nw + nb + tx];
    tile[yy][tx] = v;
  }
  __syncthreads();
  for (int yy = ty; yy < 32; yy += 8) {
    int n = nb + yy;
    if (n >= Nw) continue;
    int k = kb + tx;
    float f = tile[tx][yy];
    short hs, ls; split_bf16(f, hs, ls);
    short* orow = BT + (size_t)n * KP + 3 * k;
    orow[0] = hs; orow[1] = ls; orow[2] = hs;
  }
}

// Wcat[k][0:256]=Wq, [256:320]=Wk, [320:324]=Ww, [324:384]=0
__global__ __launch_bounds__(256) void pack_wcat_k(
    const float* __restrict__ Wq, const float* __restrict__ Wk,
    const float* __restrict__ Ww, float* __restrict__ Wcat)
{
  int idx = blockIdx.x * 256 + threadIdx.x;
  if (idx >= 1024 * NSTR) return;
  int k = idx / NSTR, n = idx - k * NSTR;
  float v = 0.f;
  if (n < 256)      v = Wq[(size_t)k * 256 + n];
  else if (n < 320) v = Wk[(size_t)k * 64 + (n - 256)];
  else if (n < 324) v = Ww[(size_t)k * 4 + (n - 320)];
  Wcat[idx] = v;
}

// bf16 MFMA GEMM, split-K over blockIdx.z: partial_z[M][N] (fp16) =
// A[M][kBeg:kBeg+kLen] * BT[N][kBeg:kBeg+kLen]^T. 128x128 tile, BK=64, 4 waves.
__global__ __launch_bounds__(256) void gemm_bf16h(
    const short* __restrict__ A, const short* __restrict__ BT,
    __half* __restrict__ C, int M, int N, int Kp, int kLen)
{
  __shared__ short As[128 * 64];
  __shared__ short Bs[128 * 64];
  const int tid = threadIdx.x;
  const int lane = tid & 63;
  const int wv = tid >> 6;
  const int m0 = blockIdx.y * 128, n0 = blockIdx.x * 128;
  const int z = blockIdx.z;
  const int kBeg = z * kLen;
  __half* Cp = C + (size_t)z * M * N;
  const int wr = (wv >> 1) * 64, wc = (wv & 1) * 64;
  f32x4 acc[4][4];
#pragma unroll
  for (int i = 0; i < 4; ++i)
#pragma unroll
    for (int j = 0; j < 4; ++j)
#pragma unroll
      for (int r = 0; r < 4; ++r) acc[i][j][r] = 0.0f;

  const int rsel = lane & 15;
  const int lrow = lane >> 3;          // 0..7
  const int lcol = (lane & 7) * 8;     // shorts
  for (int k0 = kBeg; k0 < kBeg + kLen; k0 += 64) {
#pragma unroll
    for (int q = 0; q < 4; ++q) {
      int c = wv * 4 + q;              // chunk 0..15 (8 rows each)
      int row = c * 8 + lrow;
      gload16(A  + (size_t)(m0 + row) * Kp + k0 + lcol, &As[c * 512]);
      gload16(BT + (size_t)(n0 + row) * Kp + k0 + lcol, &Bs[c * 512]);
    }
    __syncthreads();
#pragma unroll
    for (int kk = 0; kk < 2; ++kk) {
      bf16x8 af[4], bfr[4];
      int kof = kk * 32 + (lane >> 4) * 8;
#pragma unroll
      for (int i = 0; i < 4; ++i) {
        af[i]  = *(const bf16x8*)&As[(wr + i * 16 + rsel) * 64 + kof];
        bfr[i] = *(const bf16x8*)&Bs[(wc + i * 16 + rsel) * 64 + kof];
      }
#pragma unroll
      for (int i = 0; i < 4; ++i)
#pragma unroll
        for (int j = 0; j < 4; ++j)
          acc[i][j] = __builtin_amdgcn_mfma_f32_16x16x32_bf16(af[i], bfr[j], acc[i][j], 0, 0, 0);
    }
    __syncthreads();
  }
  const int er = m0 + wr + (lane >> 4) * 4;
  const int ec = n0 + wc + rsel;
#pragma unroll
  for (int i = 0; i < 4; ++i)
#pragma unroll
    for (int j = 0; j < 4; ++j)
#pragma unroll
      for (int r = 0; r < 4; ++r)
        Cp[(size_t)(er + i * 16 + r) * N + ec + j * 16] = __float2half_rn(acc[i][j][r]);
}

// fp32 indexer GEMM: C[M][384] = A[M][1024] * Wcat[1024][384].
// 32x64 tile, 128 threads, 4x4/thread, grid (6,128)=768 blocks.
__global__ __launch_bounds__(128) void gemm_idx_k(
    const float* __restrict__ A, const float* __restrict__ Bw, float* __restrict__ C)
{
  __shared__ float As[16][36];
  __shared__ float Bs[16][68];
  int n0 = blockIdx.x * 64, m0 = blockIdx.y * 32;
  int tid = threadIdx.x;
  int tr = tid >> 4;        // 0..7 -> rows tr*4..+3
  int tc = tid & 15;        // 0..15 -> cols tc*4..+3
  float acc[4][4];
#pragma unroll
  for (int i = 0; i < 4; ++i)
#pragma unroll
    for (int j = 0; j < 4; ++j) acc[i][j] = 0.f;

  for (int k0 = 0; k0 < 1024; k0 += 16) {
    {
      int lin = tid * 4;
      int row = lin >> 4, kk = lin & 15;
      float4 av = *(const float4*)(A + (size_t)(m0 + row) * 1024 + k0 + kk);
      As[kk + 0][row] = av.x; As[kk + 1][row] = av.y;
      As[kk + 2][row] = av.z; As[kk + 3][row] = av.w;
      int lin2 = tid * 8;
      int bk = lin2 >> 6, bc = lin2 & 63;
      const float* bp = Bw + (size_t)(k0 + bk) * NSTR + n0 + bc;
      *(float4*)&Bs[bk][bc]     = *(const float4*)(bp);
      *(float4*)&Bs[bk][bc + 4] = *(const float4*)(bp + 4);
    }
    __syncthreads();
#pragma unroll
    for (int k = 0; k < 16; ++k) {
      float a[4], b[4];
      *(float4*)&a[0] = *(const float4*)&As[k][tr * 4];
      *(float4*)&b[0] = *(const float4*)&Bs[k][tc * 4];
#pragma unroll
      for (int i = 0; i < 4; ++i)
#pragma unroll
        for (int j = 0; j < 4; ++j)
          acc[i][j] = fmaf(a[i], b[j], acc[i][j]);
    }
    __syncthreads();
  }
#pragma unroll
  for (int i = 0; i < 4; ++i)
    *(float4*)(C + (size_t)(m0 + tr * 4 + i) * NSTR + n0 + tc * 4) = *(float4*)&acc[i][0];
}

// P (2 fp16 partials, stride ROWS*3072) -> sum -> RoPE(q,k) + fp16; Q pre-scaled 1/8.
__global__ __launch_bounds__(256) void qkv_post_k(
    const __half* __restrict__ P, const float* __restrict__ ct, const float* __restrict__ st,
    __half* __restrict__ Qh, __half* __restrict__ Kh, __half* __restrict__ Vh)
{
  int idx = blockIdx.x * 256 + threadIdx.x;
  if (idx >= ROWS * 384) return;
  int m = idx / 384;
  int g = idx - m * 384;
  int col0 = g * 8;
  const __half* c0 = P + (size_t)m * 3072 + col0;
  const __half* c1 = c0 + (size_t)ROWS * 3072;
  float4 u = *(const float4*)c0;
  float4 v = *(const float4*)c1;
  const __half2* hu = (const __half2*)&u;
  const __half2* hv = (const __half2*)&v;
  float a[8];
#pragma unroll
  for (int c = 0; c < 4; ++c) {
    float2 x = __half22float2(hu[c]);
    float2 y = __half22float2(hv[c]);
    a[2*c]   = x.x + y.x;
    a[2*c+1] = x.y + y.y;
  }
  int sec = col0 >> 10;
  int cin = col0 & 1023;
  size_t orow = (size_t)m * 1024 + cin;
  if (sec == 2) {
    __half2 hh[4];
#pragma unroll
    for (int c = 0; c < 4; ++c) hh[c] = __floats2half2_rn(a[2*c], a[2*c+1]);
    *(float4*)(Vh + orow) = *(float4*)hh;
  } else {
    int t = m & (SS - 1);
    int jb = (cin & 63) >> 1;
    float o[8];
#pragma unroll
    for (int c = 0; c < 4; ++c) {
      float cv = ct[t * 32 + jb + c], sv = st[t * 32 + jb + c];
      float x1 = a[2*c], x2 = a[2*c+1];
      o[2*c]   = x1 * cv - x2 * sv;
      o[2*c+1] = x2 * cv + x1 * sv;
    }
    if (sec == 0) {
#pragma unroll
      for (int c = 0; c < 8; ++c) o[c] *= 0.125f;   // fold 1/sqrt(64)
    }
    __half2 hh[4];
#pragma unroll
    for (int c = 0; c < 4; ++c) hh[c] = __floats2half2_rn(o[2*c], o[2*c+1]);
    __half* dst = (sec == 0) ? Qh : Kh;
    *(float4*)(dst + orow) = *(float4*)hh;
  }
}

// Vh (b,s,h*64+d) -> VhT [(b*16+h)*64+d][s]
__global__ __launch_bounds__(256) void vt_k(
    const __half* __restrict__ Vh, __half* __restrict__ VhT)
{
  int st = blockIdx.x, bh = blockIdx.y;
  int b = bh >> 4, h = bh & 15;
  int s0 = st * 64;
  __shared__ __half tile[64][65];
  int tid = threadIdx.x;
#pragma unroll
  for (int rnd = 0; rnd < 2; ++rnd) {
    int row = (tid >> 3) + rnd * 32;
    int c8 = (tid & 7) * 8;
    *(float4*)&tile[row][c8] =
        *(const float4*)(Vh + ((size_t)b * SS + s0 + row) * 1024 + h * 64 + c8);
  }
  __syncthreads();
#pragma unroll
  for (int rnd = 0; rnd < 2; ++rnd) {
    int d = (tid >> 3) + rnd * 32;
    int s8 = (tid & 7) * 8;
    __half tmp[8];
#pragma unroll
    for (int j = 0; j < 8; ++j) tmp[j] = tile[s8 + j][d];
    *(float4*)(VhT + ((size_t)bh * 64 + d) * 2048 + s0 + s8) = *(float4*)tmp;
  }
}

// Per (b,t): indexer scores for s<=t (fp32, per-output chain identical to prior
// rounds), exact top-512 radix select (stable lowest-index ties), 2048-bit mask.
// R12 body exactly; only the block->t mapping is LPT (longest blocks first).
__global__ __launch_bounds__(256) void idx_topk_k(
    const float* __restrict__ Ccat, u32* __restrict__ msk)
{
  int b = blockIdx.y;
  int t = SS - 1 - blockIdx.x;      // LPT: longest blocks dispatch first
  int tid = threadIdx.x;
  int lane = tid & 63;
  int wv = tid >> 6;
  if (t < TOPK) {  // -1e9 ties => selection is exactly [0..511]
    if (tid < 64)
      msk[((size_t)b * SS + t) * 64 + tid] = (tid < 16) ? 0xFFFFFFFFu : 0u;
    return;
  }
  __shared__ u32 uk[SS];        // 8KB monotonic keys
  __shared__ u32 hist[256];
  __shared__ u32 w[64];
  __shared__ u32 s_bsel, s_above;

  if (tid < 64) w[tid] = 0u;

  const float4* qrow = (const float4*)(Ccat + ((size_t)b * SS + t) * NSTR);
  const float* wrow = Ccat + ((size_t)b * SS + t) * NSTR + 320;
  float w0 = wrow[0], w1 = wrow[1], w2 = wrow[2], w3 = wrow[3];

  // ---- scores -> keys (per-output chain identical to prior rounds) ----
#pragma unroll 1
  for (int s0 = 0; s0 <= t; s0 += 256) {
    int s = s0 + tid;
    if (s <= t) {
      const float4* kp = (const float4*)(Ccat + ((size_t)b * SS + s) * NSTR + 256);
      float a0 = 0.f, a1 = 0.f, a2 = 0.f, a3 = 0.f;
#pragma unroll
      for (int d4 = 0; d4 < 16; ++d4) {
        float4 kv = kp[d4];
        float4 q0 = qrow[d4];
        float4 q1 = qrow[16 + d4];
        float4 q2 = qrow[32 + d4];
        float4 q3 = qrow[48 + d4];
        a0 += q0.x * kv.x + q0.y * kv.y + q0.z * kv.z + q0.w * kv.w;
        a1 += q1.x * kv.x + q1.y * kv.y + q1.z * kv.z + q1.w * kv.w;
        a2 += q2.x * kv.x + q2.y * kv.y + q2.z * kv.z + q2.w * kv.w;
        a3 += q3.x * kv.x + q3.y * kv.y + q3.z * kv.z + q3.w * kv.w;
      }
      float v = fmaxf(a0, 0.f) * w0 + fmaxf(a1, 0.f) * w1 +
                fmaxf(a2, 0.f) * w2 + fmaxf(a3, 0.f) * w3;
      uk[s] = fkey(v);
    }
  }

  // ---- 4-pass radix: threshold key ----
  unsigned krem = TOPK;
  unsigned prefix = 0;
#pragma unroll 1
  for (int p = 0; p < 4; ++p) {
    int shift = 24 - 8 * p;
    u32 maskAbove = (p == 0) ? 0u : (0xFFFFFFFFu << (shift + 8));
    hist[tid] = 0u;
    __syncthreads();
#pragma unroll 1
    for (int s0 = 0; s0 <= t; s0 += 256) {
      int s = s0 + tid;
      if (s <= t) {
        u32 key = uk[s];
        if ((key & maskAbove) == prefix)
          atomicAdd(&hist[(key >> shift) & 255], 1u);
      }
    }
    __syncthreads();
    // wave-0 suffix scan of 256 bins (4 bins/lane), no inner barriers
    if (wv == 0) {
      uint4 hv = *(uint4*)&hist[lane * 4];
      u32 lsum = hv.x + hv.y + hv.z + hv.w;
      u32 x = lsum;
#pragma unroll
      for (int off = 1; off < 64; off <<= 1) {
        u32 y = __shfl_down(x, off);
        x += (lane + off < 64) ? y : 0u;
      }
      u32 esuf = x - lsum;            // suffix over lanes > L
      u32 S3 = esuf + hv.w;
      u32 S2 = S3 + hv.z;
      u32 S1 = S2 + hv.y;
      u32 S0 = S1 + hv.x;
      if (S0 >= krem && S1 < krem)  { s_bsel = lane * 4 + 0; s_above = S1; }
      if (S1 >= krem && S2 < krem)  { s_bsel = lane * 4 + 1; s_above = S2; }
      if (S2 >= krem && S3 < krem)  { s_bsel = lane * 4 + 2; s_above = S3; }
      if (S3 >= krem && esuf < krem){ s_bsel = lane * 4 + 3; s_above = esuf; }
    }
    __syncthreads();
    prefix |= (s_bsel << shift);
    krem -= s_above;
  }

  u32 Tkey = prefix;
  unsigned kfin = krem;               // # of ==Tkey to take (lowest indices)

  // ---- collect > Tkey: ballot word-OR straight into the bitmask ----
#pragma unroll 1
  for (int s0 = 0; s0 <= t; s0 += 256) {
    int s = s0 + tid;
    bool pred = (s <= t) && (uk[s] > Tkey);
    unsigned long long mba = __ballot(pred);
    int wbase = (s0 + wv * 64) >> 5;
    if (lane == 0 && (u32)mba) atomicOr(&w[wbase], (u32)mba);
    if (lane == 32 && (u32)(mba >> 32)) atomicOr(&w[wbase + 1], (u32)(mba >> 32));
  }
  // ---- collect == Tkey, lowest-index-first (wave 0) ----
  if (wv == 0) {
    unsigned taken = 0;
#pragma unroll 1
    for (int s0 = 0; s0 <= t && taken < kfin; s0 += 64) {
      int s = s0 + lane;
      bool pred = (s <= t) && (uk[s] == Tkey);
      unsigned long long mba = __ballot(pred);
      unsigned pre = (unsigned)__popcll(mba & ((1ull << lane) - 1ull));
      if (pred && (taken + pre) < kfin)
        atomicOr(&w[s >> 5], 1u << (s & 31));
      taken += (unsigned)__popcll(mba);
    }
  }
  __syncthreads();
  if (tid < 64) msk[((size_t)b * SS + t) * 64 + tid] = w[tid];
}

// Dense masked flash attention, f16 MFMA. Block = (b,h, 64-query tile).
// Emits split-bf16 triplets (hi,hi,lo) directly into Aattn for the out-proj GEMM.
__global__ __launch_bounds__(256) void attn_dense_k(
    const __half* __restrict__ Qh, const __half* __restrict__ Kh,
    const __half* __restrict__ VhT, const u32* __restrict__ msk,
    short* __restrict__ Aattn)
{
  int bid = blockIdx.x;
  int xcd = bid & 7, loc = bid >> 3;
  int bh = xcd * 4 + (loc >> 5);       // 4 (b,h) pairs per XCD -> K/V L2-resident
  int qt = loc & 31;
  int b = bh >> 4, h = bh & 15;
  int t0 = qt * 64;

  const int tid = threadIdx.x;
  const int lane = tid & 63;
  const int wv = tid >> 6;
  const int l15 = lane & 15;
  const int g = lane >> 4;

  __shared__ short lds[12800];          // Ks 4096 | Vt 4096 | Ps 4*1088 | mask 256
  short* Ks = lds;                      // [64 keys][8 chunks] XOR-swizzled
  short* Vt = lds + 4096;               // [64 dims][8 chunks] XOR-swizzled
  short* Ps = lds + 8192 + wv * 1088;   // per-wave [16 queries][68]
  u32* mlds = (u32*)(lds + 12544);      // [64 queries][2 words]

  const size_t brow = (size_t)b * SS;

  // Q A-fragments (m = this wave's 16 queries), resident in regs
  f16x8 qf0, qf1;
  {
    const __half* qp = Qh + (brow + t0 + wv * 16 + l15) * 1024 + h * 64 + g * 8;
    qf0 = *(const f16x8*)(qp);
    qf1 = *(const f16x8*)(qp + 32);
  }

  f32x4 accO[4];
#pragma unroll
  for (int n2 = 0; n2 < 4; ++n2)
#pragma unroll
    for (int r = 0; r < 4; ++r) accO[n2][r] = 0.f;
  float mRun[4] = {-1e30f, -1e30f, -1e30f, -1e30f};
  float sRun[4] = {0.f, 0.f, 0.f, 0.f};

  const int srow = lane >> 3;           // staging row within 8-row group
  const int scp  = (lane & 7) ^ srow;   // pre-swizzled source chunk

#pragma unroll 1
  for (int kt = 0; kt < 32; ++kt) {
    int kt0 = kt * 64;
    // ---- stage K tile, V^T tile (DMA, linear dest + inverse-swizzled src), mask ----
#pragma unroll
    for (int q = 0; q < 2; ++q) {
      int j = wv * 2 + q;
      gload16(Kh + (brow + kt0 + j * 8 + srow) * 1024 + h * 64 + scp * 8, Ks + j * 512);
      gload16(VhT + ((size_t)(bh * 64 + j * 8 + srow)) * 2048 + kt0 + scp * 8, Vt + j * 512);
    }
    if (tid < 128)
      mlds[tid] = msk[(brow + t0 + (tid >> 1)) * 64 + kt * 2 + (tid & 1)];
    __syncthreads();

    // ---- QK^T: D[m=query][n=key] ----
    f32x4 s4[4];
#pragma unroll
    for (int ns = 0; ns < 4; ++ns) {
#pragma unroll
      for (int r = 0; r < 4; ++r) s4[ns][r] = 0.f;
      int rowk = ns * 16 + l15;
      int cp0 = g ^ (rowk & 7);
      int cp1 = (4 + g) ^ (rowk & 7);
      f16x8 kf0 = *(const f16x8*)&Ks[rowk * 64 + cp0 * 8];
      f16x8 kf1 = *(const f16x8*)&Ks[rowk * 64 + cp1 * 8];
      s4[ns] = __builtin_amdgcn_mfma_f32_16x16x32_f16(qf0, kf0, s4[ns], 0, 0, 0);
      s4[ns] = __builtin_amdgcn_mfma_f32_16x16x32_f16(qf1, kf1, s4[ns], 0, 0, 0);
    }

    // ---- masked online softmax (per query row r; keys across l15 x ns) ----
#pragma unroll
    for (int r = 0; r < 4; ++r) {
      int qb2 = (wv * 16 + g * 4 + r) * 2;
      u32 w0 = mlds[qb2];
      u32 w1 = mlds[qb2 + 1];
      float le[4];
#pragma unroll
      for (int ns = 0; ns < 4; ++ns) {
        u32 w = (ns < 2) ? w0 : w1;
        int bit = (ns & 1) * 16 + l15;
        float l = s4[ns][r];
        le[ns] = ((w >> bit) & 1u) ? l : -1e30f;
      }
      float cm = fmaxf(fmaxf(le[0], le[1]), fmaxf(le[2], le[3]));
      cm = fmaxf(cm, __shfl_xor(cm, 1));
      cm = fmaxf(cm, __shfl_xor(cm, 2));
      cm = fmaxf(cm, __shfl_xor(cm, 4));
      cm = fmaxf(cm, __shfl_xor(cm, 8));
      float mn = fmaxf(mRun[r], cm);
      float fac = __expf(mRun[r] - mn);
      mRun[r] = mn;
      float sum = 0.f;
#pragma unroll
      for (int ns = 0; ns < 4; ++ns) {
        float ee = __expf(le[ns] - mn);
        ee = (le[ns] < -1e29f) ? 0.f : ee;   // masked -> exactly 0
        sum += ee;
        Ps[(g * 4 + r) * 68 + ns * 16 + l15] =
            (short)__half_as_ushort(__float2half_rn(ee));
      }
      sum += __shfl_xor(sum, 1);
      sum += __shfl_xor(sum, 2);
      sum += __shfl_xor(sum, 4);
      sum += __shfl_xor(sum, 8);
      sRun[r] = sRun[r] * fac + sum;
#pragma unroll
      for (int n2 = 0; n2 < 4; ++n2) accO[n2][r] *= fac;
    }

    // ---- PV: D[m=query][n=dim] += P * V ----
    f16x8 pa0, pa1;
    {
      const short* pp = &Ps[l15 * 68 + g * 8];
      float2 lo0 = *(const float2*)(pp);
      float2 hi0 = *(const float2*)(pp + 4);
      float2 lo1 = *(const float2*)(pp + 32);
      float2 hi1 = *(const float2*)(pp + 36);
      float4 c0 = make_float4(lo0.x, lo0.y, hi0.x, hi0.y);
      float4 c1 = make_float4(lo1.x, lo1.y, hi1.x, hi1.y);
      pa0 = *(const f16x8*)&c0;
      pa1 = *(const f16x8*)&c1;
    }
#pragma unroll
    for (int n2 = 0; n2 < 4; ++n2) {
      int rowd = n2 * 16 + l15;
      int cp0 = g ^ (rowd & 7);
      int cp1 = (4 + g) ^ (rowd & 7);
      f16x8 vf0 = *(const f16x8*)&Vt[rowd * 64 + cp0 * 8];
      f16x8 vf1 = *(const f16x8*)&Vt[rowd * 64 + cp1 * 8];
      accO[n2] = __builtin_amdgcn_mfma_f32_16x16x32_f16(pa0, vf0, accO[n2], 0, 0, 0);
      accO[n2] = __builtin_amdgcn_mfma_f32_16x16x32_f16(pa1, vf1, accO[n2], 0, 0, 0);
    }
    __syncthreads();
  }

#pragma unroll
  for (int r = 0; r < 4; ++r) {
    float inv = 1.0f / sRun[r];
    size_t grow = brow + t0 + wv * 16 + g * 4 + r;
    short* arow = Aattn + grow * 3072;
#pragma unroll
    for (int n2 = 0; n2 < 4; ++n2) {
      int col = h * 64 + n2 * 16 + l15;
      float v = accO[n2][r] * inv;
      short hs, ls; split_bf16(v, hs, ls);
      short* ap = arow + 3 * col;
      ap[0] = hs; ap[1] = hs; ap[2] = ls;
    }
  }
}

// out = sum of 3 fp16 out-proj partials (stride ROWS*1024)
__global__ __launch_bounds__(256) void redout_k(
    const __half* __restrict__ O, float* __restrict__ out)
{
  int idx = blockIdx.x * 256 + threadIdx.x;   // 8 elems/thread
  if (idx >= ROWS * 1024 / 8) return;
  const size_t PS = (size_t)ROWS * 1024;
  float4 u0 = *((const float4*)O + idx);
  float4 u1 = *((const float4*)(O + PS) + idx);
  float4 u2 = *((const float4*)(O + 2 * PS) + idx);
  const __half2* h0 = (const __half2*)&u0;
  const __half2* h1 = (const __half2*)&u1;
  const __half2* h2 = (const __half2*)&u2;
  float o[8];
#pragma unroll
  for (int c = 0; c < 4; ++c) {
    float2 a = __half22float2(h0[c]);
    float2 b = __half22float2(h1[c]);
    float2 d = __half22float2(h2[c]);
    o[2*c]   = a.x + b.x + d.x;
    o[2*c+1] = a.y + b.y + d.y;
  }
  float* op = out + (size_t)idx * 8;
  *(float4*)(op)     = make_float4(o[0], o[1], o[2], o[3]);
  *(float4*)(op + 4) = make_float4(o[4], o[5], o[6], o[7]);
}

extern "C" void kernel_launch(void* const* d_in, const int* in_sizes, int n_in,
                              void* d_out, int out_size, void* d_ws, size_t ws_size,
                              hipStream_t stream) {
  const float* x    = (const float*)d_in[0];
  const float* Wqkv = (const float*)d_in[1];
  const float* Wo   = (const float*)d_in[2];
  const float* Wq   = (const float*)d_in[3];
  const float* Wk   = (const float*)d_in[4];
  const float* Ww   = (const float*)d_in[5];
  float* out = (float*)d_out;

  float* fws = (float*)d_ws;
  size_t o = 0;
  __half* Qh    = (__half*)(fws + o);  o += (size_t)ROWS * 512;
  __half* Kh    = (__half*)(fws + o);  o += (size_t)ROWS * 512;
  __half* Vh    = (__half*)(fws + o);  o += (size_t)ROWS * 512;
  float*  ct    = fws + o;             o += (size_t)SS * 32;
  float*  st    = fws + o;             o += (size_t)SS * 32;
  float*  Ccat  = fws + o;             o += (size_t)ROWS * NSTR;       // fused qi|ki|w (padded)
  short*  BTwo  = (short*)(fws + o);   o += (size_t)1024 * KP / 2;
  short*  BTq   = (short*)(fws + o);   o += (size_t)3072 * KP / 2;
  short*  Ax    = (short*)(fws + o);                                   // aliased (ROWS*KP shorts):
  float*  Wcat  = fws + o + (size_t)ROWS * 1024;                       //  Wcat in dead tail of Ax
  /* region size */                    o += (size_t)ROWS * KP / 2;
  // Cbuf region (ROWS*3072 floats), time-multiplexed:
  //   phase 1: Ph = 2 fp16 qkv partials (2 x ROWS*3072 halves = whole region)
  //   phase 2 (post qkv_post): VhT (+8M fl), msk (+10.5M fl), Aattn ([0,6.3M fl))
  __half* Ph    = (__half*)(fws + o);
  short*  Aattn = (short*)(fws + o);
  __half* VhT   = (__half*)(fws + o + (size_t)8 * 1024 * 1024);
  u32*    msk   = (u32*)(fws + o + (size_t)10500 * 1024);
  o += (size_t)ROWS * 3072;
  // out-proj partials: 3 x ROWS*1024 halves == Qh+Kh+Vh region (dead by then)
  __half* Oparts = (__half*)Qh;

  rope_tab_k<<<dim3((SS * 32 + 255) / 256), dim3(256), 0, stream>>>(ct, st);

  // packs for the two MFMA GEMMs
  pack_a_k<<<dim3(ROWS * KDIM / 4 / 256), dim3(256), 0, stream>>>(x, Ax, ROWS * KDIM / 4);
  pack_bt_k<<<dim3(3072 / 32, 32), dim3(256), 0, stream>>>(Wqkv, BTq, 3072);
  pack_bt_k<<<dim3(1024 / 32, 32), dim3(256), 0, stream>>>(Wo, BTwo, 1024);

  // qkv GEMM (split-bf16 MFMA, split-K x2 -> fp16 partials)
  gemm_bf16h<<<dim3(3072 / 128, ROWS / 128, 2), dim3(256), 0, stream>>>(
      Ax, BTq, Ph, ROWS, 3072, KP, KP / 2);
  qkv_post_k<<<dim3((ROWS * 384 + 255) / 256), dim3(256), 0, stream>>>(Ph, ct, st, Qh, Kh, Vh);
  vt_k<<<dim3(SS / 64, BB * HH), dim3(256), 0, stream>>>(Vh, VhT);

  // fused indexer projections in fp32 (bit-identical chain; feeds exact top-k)
  pack_wcat_k<<<dim3((1024 * NSTR + 255) / 256), dim3(256), 0, stream>>>(Wq, Wk, Ww, Wcat);
  gemm_idx_k<<<dim3(NSTR / 64, ROWS / 32), dim3(128), 0, stream>>>(x, Wcat, Ccat);

  idx_topk_k<<<dim3(SS, BB), dim3(256), 0, stream>>>(Ccat, msk);
  attn_dense_k<<<dim3(1024), dim3(256), 0, stream>>>(Qh, Kh, VhT, msk, Aattn);

  // out = attn @ Wo (split-bf16 MFMA, split-K x3 -> fp16 partials in dead Qh/Kh/Vh)
  gemm_bf16h<<<dim3(1024 / 128, ROWS / 128, 3), dim3(256), 0, stream>>>(
      Aattn, BTwo, Oparts, ROWS, 1024, KP, KP / 3);
  redout_k<<<dim3(ROWS * 1024 / 8 / 256), dim3(256), 0, stream>>>(Oparts, out);
}

// Round 18
// 465.032 us; speedup vs baseline: 1.4188x; 1.1410x over previous
//
#include <hip/hip_runtime.h>
#include <hip/hip_fp16.h>
#include <hip/hip_bf16.h>
#include <math.h>

#define BB 2
#define SS 2048
#define HH 16
#define TOPK 512
#define ROWS (BB*SS)
#define KDIM 1024
#define KP 3072      // 3*KDIM (split-bf16 tripled K)
#define NSTR 384     // 256 qi | 64 ki | 4 w | 60 zero-pad

using bf16x8 = __attribute__((ext_vector_type(8))) short;
using f32x4  = __attribute__((ext_vector_type(4))) float;
typedef _Float16 f16x8 __attribute__((ext_vector_type(8)));
typedef unsigned int u32;

__device__ __forceinline__ void gload16(const void* g, void* l) {
  __builtin_amdgcn_global_load_lds(
      (const __attribute__((address_space(1))) u32*)g,
      (__attribute__((address_space(3))) u32*)l, 16, 0, 0);
}

__device__ __forceinline__ void split_bf16(float f, short& hi, short& lo) {
  __hip_bfloat16 h = __float2bfloat16(f);
  float fh = __bfloat162float(h);
  __hip_bfloat16 l = __float2bfloat16(f - fh);
  hi = *reinterpret_cast<short*>(&h);
  lo = *reinterpret_cast<short*>(&l);
}

__device__ __forceinline__ unsigned fkey(float f) {
  unsigned u = __float_as_uint(f);
  if ((u << 1) == 0u) u = 0u;             // canonicalize -0.0 -> +0.0
  return (u & 0x80000000u) ? ~u : (u | 0x80000000u);
}

__global__ void rope_tab_k(float* __restrict__ ct, float* __restrict__ st) {
  int idx = blockIdx.x * blockDim.x + threadIdx.x;
  if (idx >= SS * 32) return;
  int s = idx >> 5, j = idx & 31;
  float theta = 1.0f / powf(10000.0f, (float)(2 * j) / 64.0f);
  float ang = (float)s * theta;
  float sv, cv;
  sincosf(ang, &sv, &cv);
  ct[idx] = cv;
  st[idx] = sv;
}

// X[M][1024] fp32 -> A[M][3072] bf16 triplets (hi,hi,lo)
__global__ __launch_bounds__(256) void pack_a_k(
    const float* __restrict__ X, short* __restrict__ A, int total4)
{
  int idx = blockIdx.x * 256 + threadIdx.x;
  if (idx >= total4) return;
  float4 v = ((const float4*)X)[idx];
  float a4[4] = {v.x, v.y, v.z, v.w};
  short o[12];
#pragma unroll
  for (int j = 0; j < 4; ++j) {
    short hs, ls; split_bf16(a4[j], hs, ls);
    o[3*j] = hs; o[3*j+1] = hs; o[3*j+2] = ls;
  }
  short* op = A + (size_t)idx * 12;
  *(short4*)(op)     = *(short4*)&o[0];
  *(short4*)(op + 4) = *(short4*)&o[4];
  *(short4*)(op + 8) = *(short4*)&o[8];
}

// W[K=1024][Nw] fp32 -> BT rows [n][3072] bf16 triplets (hi,lo,hi)
__global__ __launch_bounds__(256) void pack_bt_k(
    const float* __restrict__ W, short* __restrict__ BT, int Nw)
{
  __shared__ float tile[32][33];
  int kb = blockIdx.y * 32, nb = blockIdx.x * 32;
  int tx = threadIdx.x & 31, ty = threadIdx.x >> 5;
  for (int yy = ty; yy < 32; yy += 8) {
    float v = 0.f;
    if (nb + tx < Nw) v = W[(size_t)(kb + yy) * Nw + nb + tx];
    tile[yy][tx] = v;
  }
  __syncthreads();
  for (int yy = ty; yy < 32; yy += 8) {
    int n = nb + yy;
    if (n >= Nw) continue;
    int k = kb + tx;
    float f = tile[tx][yy];
    short hs, ls; split_bf16(f, hs, ls);
    short* orow = BT + (size_t)n * KP + 3 * k;
    orow[0] = hs; orow[1] = ls; orow[2] = hs;
  }
}

// Wcat[k][0:256]=Wq, [256:320]=Wk, [320:324]=Ww, [324:384]=0
__global__ __launch_bounds__(256) void pack_wcat_k(
    const float* __restrict__ Wq, const float* __restrict__ Wk,
    const float* __restrict__ Ww, float* __restrict__ Wcat)
{
  int idx = blockIdx.x * 256 + threadIdx.x;
  if (idx >= 1024 * NSTR) return;
  int k = idx / NSTR, n = idx - k * NSTR;
  float v = 0.f;
  if (n < 256)      v = Wq[(size_t)k * 256 + n];
  else if (n < 320) v = Wk[(size_t)k * 64 + (n - 256)];
  else if (n < 324) v = Ww[(size_t)k * 4 + (n - 320)];
  Wcat[idx] = v;
}

// Ccat ki slice -> kiT4[b][d4][s] (float4 of dims 4*d4..4*d4+3, contiguous in s)
__global__ __launch_bounds__(256) void tr_ki_k(
    const float* __restrict__ Ccat, float4* __restrict__ kiT4)
{
  int idx = blockIdx.x * 256 + threadIdx.x;
  if (idx >= BB * 16 * SS) return;
  int b = idx >> 15;
  int rem = idx & 32767;
  int d4 = rem >> 11;
  int s = rem & 2047;
  kiT4[idx] = *(const float4*)(Ccat + ((size_t)b * SS + s) * NSTR + 256 + 4 * d4);
}

// bf16 MFMA GEMM, split-K over blockIdx.z: partial_z[M][N] (fp16) =
// A[M][kBeg:kBeg+kLen] * BT[N][kBeg:kBeg+kLen]^T. 128x128 tile, BK=64, 4 waves.
__global__ __launch_bounds__(256) void gemm_bf16h(
    const short* __restrict__ A, const short* __restrict__ BT,
    __half* __restrict__ C, int M, int N, int Kp, int kLen)
{
  __shared__ short As[128 * 64];
  __shared__ short Bs[128 * 64];
  const int tid = threadIdx.x;
  const int lane = tid & 63;
  const int wv = tid >> 6;
  const int m0 = blockIdx.y * 128, n0 = blockIdx.x * 128;
  const int z = blockIdx.z;
  const int kBeg = z * kLen;
  __half* Cp = C + (size_t)z * M * N;
  const int wr = (wv >> 1) * 64, wc = (wv & 1) * 64;
  f32x4 acc[4][4];
#pragma unroll
  for (int i = 0; i < 4; ++i)
#pragma unroll
    for (int j = 0; j < 4; ++j)
#pragma unroll
      for (int r = 0; r < 4; ++r) acc[i][j][r] = 0.0f;

  const int rsel = lane & 15;
  const int lrow = lane >> 3;          // 0..7
  const int lcol = (lane & 7) * 8;     // shorts
  for (int k0 = kBeg; k0 < kBeg + kLen; k0 += 64) {
#pragma unroll
    for (int q = 0; q < 4; ++q) {
      int c = wv * 4 + q;              // chunk 0..15 (8 rows each)
      int row = c * 8 + lrow;
      gload16(A  + (size_t)(m0 + row) * Kp + k0 + lcol, &As[c * 512]);
      gload16(BT + (size_t)(n0 + row) * Kp + k0 + lcol, &Bs[c * 512]);
    }
    __syncthreads();
#pragma unroll
    for (int kk = 0; kk < 2; ++kk) {
      bf16x8 af[4], bfr[4];
      int kof = kk * 32 + (lane >> 4) * 8;
#pragma unroll
      for (int i = 0; i < 4; ++i) {
        af[i]  = *(const bf16x8*)&As[(wr + i * 16 + rsel) * 64 + kof];
        bfr[i] = *(const bf16x8*)&Bs[(wc + i * 16 + rsel) * 64 + kof];
      }
#pragma unroll
      for (int i = 0; i < 4; ++i)
#pragma unroll
        for (int j = 0; j < 4; ++j)
          acc[i][j] = __builtin_amdgcn_mfma_f32_16x16x32_bf16(af[i], bfr[j], acc[i][j], 0, 0, 0);
    }
    __syncthreads();
  }
  const int er = m0 + wr + (lane >> 4) * 4;
  const int ec = n0 + wc + rsel;
#pragma unroll
  for (int i = 0; i < 4; ++i)
#pragma unroll
    for (int j = 0; j < 4; ++j)
#pragma unroll
      for (int r = 0; r < 4; ++r)
        Cp[(size_t)(er + i * 16 + r) * N + ec + j * 16] = __float2half_rn(acc[i][j][r]);
}

// fp32 indexer GEMM: C[M][384] = A[M][1024] * Wcat[1024][384].
// 32x64 tile, 128 threads, 4x4/thread, grid (6,128)=768 blocks.
__global__ __launch_bounds__(128) void gemm_idx_k(
    const float* __restrict__ A, const float* __restrict__ Bw, float* __restrict__ C)
{
  __shared__ float As[16][36];
  __shared__ float Bs[16][68];
  int n0 = blockIdx.x * 64, m0 = blockIdx.y * 32;
  int tid = threadIdx.x;
  int tr = tid >> 4;        // 0..7 -> rows tr*4..+3
  int tc = tid & 15;        // 0..15 -> cols tc*4..+3
  float acc[4][4];
#pragma unroll
  for (int i = 0; i < 4; ++i)
#pragma unroll
    for (int j = 0; j < 4; ++j) acc[i][j] = 0.f;

  for (int k0 = 0; k0 < 1024; k0 += 16) {
    {
      int lin = tid * 4;
      int row = lin >> 4, kk = lin & 15;
      float4 av = *(const float4*)(A + (size_t)(m0 + row) * 1024 + k0 + kk);
      As[kk + 0][row] = av.x; As[kk + 1][row] = av.y;
      As[kk + 2][row] = av.z; As[kk + 3][row] = av.w;
      int lin2 = tid * 8;
      int bk = lin2 >> 6, bc = lin2 & 63;
      const float* bp = Bw + (size_t)(k0 + bk) * NSTR + n0 + bc;
      *(float4*)&Bs[bk][bc]     = *(const float4*)(bp);
      *(float4*)&Bs[bk][bc + 4] = *(const float4*)(bp + 4);
    }
    __syncthreads();
#pragma unroll
    for (int k = 0; k < 16; ++k) {
      float a[4], b[4];
      *(float4*)&a[0] = *(const float4*)&As[k][tr * 4];
      *(float4*)&b[0] = *(const float4*)&Bs[k][tc * 4];
#pragma unroll
      for (int i = 0; i < 4; ++i)
#pragma unroll
        for (int j = 0; j < 4; ++j)
          acc[i][j] = fmaf(a[i], b[j], acc[i][j]);
    }
    __syncthreads();
  }
#pragma unroll
  for (int i = 0; i < 4; ++i)
    *(float4*)(C + (size_t)(m0 + tr * 4 + i) * NSTR + n0 + tc * 4) = *(float4*)&acc[i][0];
}

// P (2 fp16 partials, stride ROWS*3072) -> sum -> RoPE(q,k) + fp16; Q pre-scaled 1/8.
__global__ __launch_bounds__(256) void qkv_post_k(
    const __half* __restrict__ P, const float* __restrict__ ct, const float* __restrict__ st,
    __half* __restrict__ Qh, __half* __restrict__ Kh, __half* __restrict__ Vh)
{
  int idx = blockIdx.x * 256 + threadIdx.x;
  if (idx >= ROWS * 384) return;
  int m = idx / 384;
  int g = idx - m * 384;
  int col0 = g * 8;
  const __half* c0 = P + (size_t)m * 3072 + col0;
  const __half* c1 = c0 + (size_t)ROWS * 3072;
  float4 u = *(const float4*)c0;
  float4 v = *(const float4*)c1;
  const __half2* hu = (const __half2*)&u;
  const __half2* hv = (const __half2*)&v;
  float a[8];
#pragma unroll
  for (int c = 0; c < 4; ++c) {
    float2 x = __half22float2(hu[c]);
    float2 y = __half22float2(hv[c]);
    a[2*c]   = x.x + y.x;
    a[2*c+1] = x.y + y.y;
  }
  int sec = col0 >> 10;
  int cin = col0 & 1023;
  size_t orow = (size_t)m * 1024 + cin;
  if (sec == 2) {
    __half2 hh[4];
#pragma unroll
    for (int c = 0; c < 4; ++c) hh[c] = __floats2half2_rn(a[2*c], a[2*c+1]);
    *(float4*)(Vh + orow) = *(float4*)hh;
  } else {
    int t = m & (SS - 1);
    int jb = (cin & 63) >> 1;
    float o[8];
#pragma unroll
    for (int c = 0; c < 4; ++c) {
      float cv = ct[t * 32 + jb + c], sv = st[t * 32 + jb + c];
      float x1 = a[2*c], x2 = a[2*c+1];
      o[2*c]   = x1 * cv - x2 * sv;
      o[2*c+1] = x2 * cv + x1 * sv;
    }
    if (sec == 0) {
#pragma unroll
      for (int c = 0; c < 8; ++c) o[c] *= 0.125f;   // fold 1/sqrt(64)
    }
    __half2 hh[4];
#pragma unroll
    for (int c = 0; c < 4; ++c) hh[c] = __floats2half2_rn(o[2*c], o[2*c+1]);
    __half* dst = (sec == 0) ? Qh : Kh;
    *(float4*)(dst + orow) = *(float4*)hh;
  }
}

// Vh (b,s,h*64+d) -> VhT [(b*16+h)*64+d][s]
__global__ __launch_bounds__(256) void vt_k(
    const __half* __restrict__ Vh, __half* __restrict__ VhT)
{
  int st = blockIdx.x, bh = blockIdx.y;
  int b = bh >> 4, h = bh & 15;
  int s0 = st * 64;
  __shared__ __half tile[64][65];
  int tid = threadIdx.x;
#pragma unroll
  for (int rnd = 0; rnd < 2; ++rnd) {
    int row = (tid >> 3) + rnd * 32;
    int c8 = (tid & 7) * 8;
    *(float4*)&tile[row][c8] =
        *(const float4*)(Vh + ((size_t)b * SS + s0 + row) * 1024 + h * 64 + c8);
  }
  __syncthreads();
#pragma unroll
  for (int rnd = 0; rnd < 2; ++rnd) {
    int d = (tid >> 3) + rnd * 32;
    int s8 = (tid & 7) * 8;
    __half tmp[8];
#pragma unroll
    for (int j = 0; j < 8; ++j) tmp[j] = tile[s8 + j][d];
    *(float4*)(VhT + ((size_t)bh * 64 + d) * 2048 + s0 + s8) = *(float4*)tmp;
  }
}

// Per (b,t): indexer scores for s<=t (fp32, per-output chain identical to prior
// rounds; ki read from transposed kiT4 -> coalesced), exact top-512 radix select
// (stable lowest-index ties), 2048-bit mask. LPT mapping.
__global__ __launch_bounds__(256) void idx_topk_k(
    const float* __restrict__ Ccat, const float4* __restrict__ kiT4,
    u32* __restrict__ msk)
{
  int b = blockIdx.y;
  int t = SS - 1 - blockIdx.x;      // LPT: longest blocks dispatch first
  int tid = threadIdx.x;
  int lane = tid & 63;
  int wv = tid >> 6;
  if (t < TOPK) {  // -1e9 ties => selection is exactly [0..511]
    if (tid < 64)
      msk[((size_t)b * SS + t) * 64 + tid] = (tid < 16) ? 0xFFFFFFFFu : 0u;
    return;
  }
  __shared__ u32 uk[SS];        // 8KB monotonic keys
  __shared__ u32 hist[256];
  __shared__ u32 w[64];
  __shared__ u32 s_bsel, s_above;

  if (tid < 64) w[tid] = 0u;

  const float4* qrow = (const float4*)(Ccat + ((size_t)b * SS + t) * NSTR);
  const float* wrow = Ccat + ((size_t)b * SS + t) * NSTR + 320;
  float w0 = wrow[0], w1 = wrow[1], w2 = wrow[2], w3 = wrow[3];
  const float4* kb = kiT4 + (size_t)b * 16 * SS;   // [16][2048] float4

  // ---- scores -> keys (chain identical; ki loads coalesced via kiT4) ----
#pragma unroll 1
  for (int s0 = 0; s0 <= t; s0 += 256) {
    int s = s0 + tid;
    if (s <= t) {
      float a0 = 0.f, a1 = 0.f, a2 = 0.f, a3 = 0.f;
#pragma unroll
      for (int d4 = 0; d4 < 16; ++d4) {
        float4 kv = kb[d4 * SS + s];
        float4 q0 = qrow[d4];
        float4 q1 = qrow[16 + d4];
        float4 q2 = qrow[32 + d4];
        float4 q3 = qrow[48 + d4];
        a0 += q0.x * kv.x + q0.y * kv.y + q0.z * kv.z + q0.w * kv.w;
        a1 += q1.x * kv.x + q1.y * kv.y + q1.z * kv.z + q1.w * kv.w;
        a2 += q2.x * kv.x + q2.y * kv.y + q2.z * kv.z + q2.w * kv.w;
        a3 += q3.x * kv.x + q3.y * kv.y + q3.z * kv.z + q3.w * kv.w;
      }
      float v = fmaxf(a0, 0.f) * w0 + fmaxf(a1, 0.f) * w1 +
                fmaxf(a2, 0.f) * w2 + fmaxf(a3, 0.f) * w3;
      uk[s] = fkey(v);
    }
  }

  // ---- 4-pass radix: threshold key ----
  unsigned krem = TOPK;
  unsigned prefix = 0;
#pragma unroll 1
  for (int p = 0; p < 4; ++p) {
    int shift = 24 - 8 * p;
    u32 maskAbove = (p == 0) ? 0u : (0xFFFFFFFFu << (shift + 8));
    hist[tid] = 0u;
    __syncthreads();
#pragma unroll 1
    for (int s0 = 0; s0 <= t; s0 += 256) {
      int s = s0 + tid;
      if (s <= t) {
        u32 key = uk[s];
        if ((key & maskAbove) == prefix)
          atomicAdd(&hist[(key >> shift) & 255], 1u);
      }
    }
    __syncthreads();
    // wave-0 suffix scan of 256 bins (4 bins/lane), no inner barriers
    if (wv == 0) {
      uint4 hv = *(uint4*)&hist[lane * 4];
      u32 lsum = hv.x + hv.y + hv.z + hv.w;
      u32 x = lsum;
#pragma unroll
      for (int off = 1; off < 64; off <<= 1) {
        u32 y = __shfl_down(x, off);
        x += (lane + off < 64) ? y : 0u;
      }
      u32 esuf = x - lsum;            // suffix over lanes > L
      u32 S3 = esuf + hv.w;
      u32 S2 = S3 + hv.z;
      u32 S1 = S2 + hv.y;
      u32 S0 = S1 + hv.x;
      if (S0 >= krem && S1 < krem)  { s_bsel = lane * 4 + 0; s_above = S1; }
      if (S1 >= krem && S2 < krem)  { s_bsel = lane * 4 + 1; s_above = S2; }
      if (S2 >= krem && S3 < krem)  { s_bsel = lane * 4 + 2; s_above = S3; }
      if (S3 >= krem && esuf < krem){ s_bsel = lane * 4 + 3; s_above = esuf; }
    }
    __syncthreads();
    prefix |= (s_bsel << shift);
    krem -= s_above;
  }

  u32 Tkey = prefix;
  unsigned kfin = krem;               // # of ==Tkey to take (lowest indices)

  // ---- collect > Tkey: ballot word-OR straight into the bitmask ----
#pragma unroll 1
  for (int s0 = 0; s0 <= t; s0 += 256) {
    int s = s0 + tid;
    bool pred = (s <= t) && (uk[s] > Tkey);
    unsigned long long mba = __ballot(pred);
    int wbase = (s0 + wv * 64) >> 5;
    if (lane == 0 && (u32)mba) atomicOr(&w[wbase], (u32)mba);
    if (lane == 32 && (u32)(mba >> 32)) atomicOr(&w[wbase + 1], (u32)(mba >> 32));
  }
  // ---- collect == Tkey, lowest-index-first (wave 0) ----
  if (wv == 0) {
    unsigned taken = 0;
#pragma unroll 1
    for (int s0 = 0; s0 <= t && taken < kfin; s0 += 64) {
      int s = s0 + lane;
      bool pred = (s <= t) && (uk[s] == Tkey);
      unsigned long long mba = __ballot(pred);
      unsigned pre = (unsigned)__popcll(mba & ((1ull << lane) - 1ull));
      if (pred && (taken + pre) < kfin)
        atomicOr(&w[s >> 5], 1u << (s & 31));
      taken += (unsigned)__popcll(mba);
    }
  }
  __syncthreads();
  if (tid < 64) msk[((size_t)b * SS + t) * 64 + tid] = w[tid];
}

// Dense masked flash attention, f16 MFMA. Block = (b,h, 64-query tile).
// Emits split-bf16 triplets (hi,hi,lo) directly into Aattn for the out-proj GEMM.
__global__ __launch_bounds__(256) void attn_dense_k(
    const __half* __restrict__ Qh, const __half* __restrict__ Kh,
    const __half* __restrict__ VhT, const u32* __restrict__ msk,
    short* __restrict__ Aattn)
{
  int bid = blockIdx.x;
  int xcd = bid & 7, loc = bid >> 3;
  int bh = xcd * 4 + (loc >> 5);       // 4 (b,h) pairs per XCD -> K/V L2-resident
  int qt = loc & 31;
  int b = bh >> 4, h = bh & 15;
  int t0 = qt * 64;

  const int tid = threadIdx.x;
  const int lane = tid & 63;
  const int wv = tid >> 6;
  const int l15 = lane & 15;
  const int g = lane >> 4;

  __shared__ short lds[12800];          // Ks 4096 | Vt 4096 | Ps 4*1088 | mask 256
  short* Ks = lds;                      // [64 keys][8 chunks] XOR-swizzled
  short* Vt = lds + 4096;               // [64 dims][8 chunks] XOR-swizzled
  short* Ps = lds + 8192 + wv * 1088;   // per-wave [16 queries][68]
  u32* mlds = (u32*)(lds + 12544);      // [64 queries][2 words]

  const size_t brow = (size_t)b * SS;

  // Q A-fragments (m = this wave's 16 queries), resident in regs
  f16x8 qf0, qf1;
  {
    const __half* qp = Qh + (brow + t0 + wv * 16 + l15) * 1024 + h * 64 + g * 8;
    qf0 = *(const f16x8*)(qp);
    qf1 = *(const f16x8*)(qp + 32);
  }

  f32x4 accO[4];
#pragma unroll
  for (int n2 = 0; n2 < 4; ++n2)
#pragma unroll
    for (int r = 0; r < 4; ++r) accO[n2][r] = 0.f;
  float mRun[4] = {-1e30f, -1e30f, -1e30f, -1e30f};
  float sRun[4] = {0.f, 0.f, 0.f, 0.f};

  const int srow = lane >> 3;           // staging row within 8-row group
  const int scp  = (lane & 7) ^ srow;   // pre-swizzled source chunk

#pragma unroll 1
  for (int kt = 0; kt < 32; ++kt) {
    int kt0 = kt * 64;
    // ---- stage K tile, V^T tile (DMA, linear dest + inverse-swizzled src), mask ----
#pragma unroll
    for (int q = 0; q < 2; ++q) {
      int j = wv * 2 + q;
      gload16(Kh + (brow + kt0 + j * 8 + srow) * 1024 + h * 64 + scp * 8, Ks + j * 512);
      gload16(VhT + ((size_t)(bh * 64 + j * 8 + srow)) * 2048 + kt0 + scp * 8, Vt + j * 512);
    }
    if (tid < 128)
      mlds[tid] = msk[(brow + t0 + (tid >> 1)) * 64 + kt * 2 + (tid & 1)];
    __syncthreads();

    // ---- QK^T: D[m=query][n=key] ----
    f32x4 s4[4];
#pragma unroll
    for (int ns = 0; ns < 4; ++ns) {
#pragma unroll
      for (int r = 0; r < 4; ++r) s4[ns][r] = 0.f;
      int rowk = ns * 16 + l15;
      int cp0 = g ^ (rowk & 7);
      int cp1 = (4 + g) ^ (rowk & 7);
      f16x8 kf0 = *(const f16x8*)&Ks[rowk * 64 + cp0 * 8];
      f16x8 kf1 = *(const f16x8*)&Ks[rowk * 64 + cp1 * 8];
      s4[ns] = __builtin_amdgcn_mfma_f32_16x16x32_f16(qf0, kf0, s4[ns], 0, 0, 0);
      s4[ns] = __builtin_amdgcn_mfma_f32_16x16x32_f16(qf1, kf1, s4[ns], 0, 0, 0);
    }

    // ---- masked online softmax (per query row r; keys across l15 x ns) ----
#pragma unroll
    for (int r = 0; r < 4; ++r) {
      int qb2 = (wv * 16 + g * 4 + r) * 2;
      u32 w0 = mlds[qb2];
      u32 w1 = mlds[qb2 + 1];
      float le[4];
#pragma unroll
      for (int ns = 0; ns < 4; ++ns) {
        u32 w = (ns < 2) ? w0 : w1;
        int bit = (ns & 1) * 16 + l15;
        float l = s4[ns][r];
        le[ns] = ((w >> bit) & 1u) ? l : -1e30f;
      }
      float cm = fmaxf(fmaxf(le[0], le[1]), fmaxf(le[2], le[3]));
      cm = fmaxf(cm, __shfl_xor(cm, 1));
      cm = fmaxf(cm, __shfl_xor(cm, 2));
      cm = fmaxf(cm, __shfl_xor(cm, 4));
      cm = fmaxf(cm, __shfl_xor(cm, 8));
      float mn = fmaxf(mRun[r], cm);
      float fac = __expf(mRun[r] - mn);
      mRun[r] = mn;
      float sum = 0.f;
#pragma unroll
      for (int ns = 0; ns < 4; ++ns) {
        float ee = __expf(le[ns] - mn);
        ee = (le[ns] < -1e29f) ? 0.f : ee;   // masked -> exactly 0
        sum += ee;
        Ps[(g * 4 + r) * 68 + ns * 16 + l15] =
            (short)__half_as_ushort(__float2half_rn(ee));
      }
      sum += __shfl_xor(sum, 1);
      sum += __shfl_xor(sum, 2);
      sum += __shfl_xor(sum, 4);
      sum += __shfl_xor(sum, 8);
      sRun[r] = sRun[r] * fac + sum;
#pragma unroll
      for (int n2 = 0; n2 < 4; ++n2) accO[n2][r] *= fac;
    }

    // ---- PV: D[m=query][n=dim] += P * V ----
    f16x8 pa0, pa1;
    {
      const short* pp = &Ps[l15 * 68 + g * 8];
      float2 lo0 = *(const float2*)(pp);
      float2 hi0 = *(const float2*)(pp + 4);
      float2 lo1 = *(const float2*)(pp + 32);
      float2 hi1 = *(const float2*)(pp + 36);
      float4 c0 = make_float4(lo0.x, lo0.y, hi0.x, hi0.y);
      float4 c1 = make_float4(lo1.x, lo1.y, hi1.x, hi1.y);
      pa0 = *(const f16x8*)&c0;
      pa1 = *(const f16x8*)&c1;
    }
#pragma unroll
    for (int n2 = 0; n2 < 4; ++n2) {
      int rowd = n2 * 16 + l15;
      int cp0 = g ^ (rowd & 7);
      int cp1 = (4 + g) ^ (rowd & 7);
      f16x8 vf0 = *(const f16x8*)&Vt[rowd * 64 + cp0 * 8];
      f16x8 vf1 = *(const f16x8*)&Vt[rowd * 64 + cp1 * 8];
      accO[n2] = __builtin_amdgcn_mfma_f32_16x16x32_f16(pa0, vf0, accO[n2], 0, 0, 0);
      accO[n2] = __builtin_amdgcn_mfma_f32_16x16x32_f16(pa1, vf1, accO[n2], 0, 0, 0);
    }
    __syncthreads();
  }

#pragma unroll
  for (int r = 0; r < 4; ++r) {
    float inv = 1.0f / sRun[r];
    size_t grow = brow + t0 + wv * 16 + g * 4 + r;
    short* arow = Aattn + grow * 3072;
#pragma unroll
    for (int n2 = 0; n2 < 4; ++n2) {
      int col = h * 64 + n2 * 16 + l15;
      float v = accO[n2][r] * inv;
      short hs, ls; split_bf16(v, hs, ls);
      short* ap = arow + 3 * col;
      ap[0] = hs; ap[1] = hs; ap[2] = ls;
    }
  }
}

// out = sum of 3 fp16 out-proj partials (stride ROWS*1024)
__global__ __launch_bounds__(256) void redout_k(
    const __half* __restrict__ O, float* __restrict__ out)
{
  int idx = blockIdx.x * 256 + threadIdx.x;   // 8 elems/thread
  if (idx >= ROWS * 1024 / 8) return;
  const size_t PS = (size_t)ROWS * 1024;
  float4 u0 = *((const float4*)O + idx);
  float4 u1 = *((const float4*)(O + PS) + idx);
  float4 u2 = *((const float4*)(O + 2 * PS) + idx);
  const __half2* h0 = (const __half2*)&u0;
  const __half2* h1 = (const __half2*)&u1;
  const __half2* h2 = (const __half2*)&u2;
  float o[8];
#pragma unroll
  for (int c = 0; c < 4; ++c) {
    float2 a = __half22float2(h0[c]);
    float2 b = __half22float2(h1[c]);
    float2 d = __half22float2(h2[c]);
    o[2*c]   = a.x + b.x + d.x;
    o[2*c+1] = a.y + b.y + d.y;
  }
  float* op = out + (size_t)idx * 8;
  *(float4*)(op)     = make_float4(o[0], o[1], o[2], o[3]);
  *(float4*)(op + 4) = make_float4(o[4], o[5], o[6], o[7]);
}

extern "C" void kernel_launch(void* const* d_in, const int* in_sizes, int n_in,
                              void* d_out, int out_size, void* d_ws, size_t ws_size,
                              hipStream_t stream) {
  const float* x    = (const float*)d_in[0];
  const float* Wqkv = (const float*)d_in[1];
  const float* Wo   = (const float*)d_in[2];
  const float* Wq   = (const float*)d_in[3];
  const float* Wk   = (const float*)d_in[4];
  const float* Ww   = (const float*)d_in[5];
  float* out = (float*)d_out;

  float* fws = (float*)d_ws;
  size_t o = 0;
  __half* Qh    = (__half*)(fws + o);  o += (size_t)ROWS * 512;
  __half* Kh    = (__half*)(fws + o);  o += (size_t)ROWS * 512;
  __half* Vh    = (__half*)(fws + o);  o += (size_t)ROWS * 512;
  float*  ct    = fws + o;             o += (size_t)SS * 32;
  float*  st    = fws + o;             o += (size_t)SS * 32;
  float*  Ccat  = fws + o;             o += (size_t)ROWS * NSTR;       // fused qi|ki|w (padded)
  short*  BTwo  = (short*)(fws + o);   o += (size_t)1024 * KP / 2;
  short*  BTq   = (short*)(fws + o);   o += (size_t)3072 * KP / 2;
  short*  Ax    = (short*)(fws + o);                                   // aliased (ROWS*KP shorts):
  float*  Wcat  = fws + o + (size_t)ROWS * 1024;                       //  Wcat in dead tail of Ax
  /* region size */                    o += (size_t)ROWS * KP / 2;
  // Cbuf region (ROWS*3072 floats), time-multiplexed:
  //   phase 1: Ph = 2 fp16 qkv partials (whole region)
  //   phase 2: Aattn [0,6.3M fl) | VhT +8M fl | msk +10.5M fl | kiT4 +11M fl
  __half* Ph    = (__half*)(fws + o);
  short*  Aattn = (short*)(fws + o);
  __half* VhT   = (__half*)(fws + o + (size_t)8 * 1024 * 1024);
  u32*    msk   = (u32*)(fws + o + (size_t)10500 * 1024);
  float4* kiT4  = (float4*)(fws + o + (size_t)11264 * 1024);
  o += (size_t)ROWS * 3072;
  // out-proj partials: 3 x ROWS*1024 halves == Qh+Kh+Vh region (dead by then)
  __half* Oparts = (__half*)Qh;

  rope_tab_k<<<dim3((SS * 32 + 255) / 256), dim3(256), 0, stream>>>(ct, st);

  // packs for the two MFMA GEMMs
  pack_a_k<<<dim3(ROWS * KDIM / 4 / 256), dim3(256), 0, stream>>>(x, Ax, ROWS * KDIM / 4);
  pack_bt_k<<<dim3(3072 / 32, 32), dim3(256), 0, stream>>>(Wqkv, BTq, 3072);
  pack_bt_k<<<dim3(1024 / 32, 32), dim3(256), 0, stream>>>(Wo, BTwo, 1024);

  // qkv GEMM (split-bf16 MFMA, split-K x2 -> fp16 partials)
  gemm_bf16h<<<dim3(3072 / 128, ROWS / 128, 2), dim3(256), 0, stream>>>(
      Ax, BTq, Ph, ROWS, 3072, KP, KP / 2);
  qkv_post_k<<<dim3((ROWS * 384 + 255) / 256), dim3(256), 0, stream>>>(Ph, ct, st, Qh, Kh, Vh);
  vt_k<<<dim3(SS / 64, BB * HH), dim3(256), 0, stream>>>(Vh, VhT);

  // fused indexer projections in fp32 (bit-identical chain; feeds exact top-k)
  pack_wcat_k<<<dim3((1024 * NSTR + 255) / 256), dim3(256), 0, stream>>>(Wq, Wk, Ww, Wcat);
  gemm_idx_k<<<dim3(NSTR / 64, ROWS / 32), dim3(128), 0, stream>>>(x, Wcat, Ccat);
  tr_ki_k<<<dim3(BB * 16 * SS / 256), dim3(256), 0, stream>>>(Ccat, kiT4);

  idx_topk_k<<<dim3(SS, BB), dim3(256), 0, stream>>>(Ccat, kiT4, msk);
  attn_dense_k<<<dim3(1024), dim3(256), 0, stream>>>(Qh, Kh, VhT, msk, Aattn);

  // out = attn @ Wo (split-bf16 MFMA, split-K x3 -> fp16 partials in dead Qh/Kh/Vh)
  gemm_bf16h<<<dim3(1024 / 128, ROWS / 128, 3), dim3(256), 0, stream>>>(
      Aattn, BTwo, Oparts, ROWS, 1024, KP, KP / 3);
  redout_k<<<dim3(ROWS * 1024 / 8 / 256), dim3(256), 0, stream>>>(Oparts, out);
}

// Round 20
// 463.404 us; speedup vs baseline: 1.4238x; 1.0035x over previous
//
#include <hip/hip_runtime.h>
#include <hip/hip_fp16.h>
#include <hip/hip_bf16.h>
#include <math.h>

#define BB 2
#define SS 2048
#define HH 16
#define TOPK 512
#define ROWS (BB*SS)
#define KDIM 1024
#define KP 3072      // 3*KDIM (split-bf16 tripled K)
#define NSTR 384     // 256 qi | 64 ki | 4 w | 60 zero-pad

using bf16x8 = __attribute__((ext_vector_type(8))) short;
using f32x4  = __attribute__((ext_vector_type(4))) float;
typedef _Float16 f16x8 __attribute__((ext_vector_type(8)));
typedef unsigned int u32;

__device__ __forceinline__ void gload16(const void* g, void* l) {
  __builtin_amdgcn_global_load_lds(
      (const __attribute__((address_space(1))) u32*)g,
      (__attribute__((address_space(3))) u32*)l, 16, 0, 0);
}

__device__ __forceinline__ void split_bf16(float f, short& hi, short& lo) {
  __hip_bfloat16 h = __float2bfloat16(f);
  float fh = __bfloat162float(h);
  __hip_bfloat16 l = __float2bfloat16(f - fh);
  hi = *reinterpret_cast<short*>(&h);
  lo = *reinterpret_cast<short*>(&l);
}

__device__ __forceinline__ unsigned fkey(float f) {
  unsigned u = __float_as_uint(f);
  if ((u << 1) == 0u) u = 0u;             // canonicalize -0.0 -> +0.0
  return (u & 0x80000000u) ? ~u : (u | 0x80000000u);
}

__global__ void rope_tab_k(float* __restrict__ ct, float* __restrict__ st) {
  int idx = blockIdx.x * blockDim.x + threadIdx.x;
  if (idx >= SS * 32) return;
  int s = idx >> 5, j = idx & 31;
  float theta = 1.0f / powf(10000.0f, (float)(2 * j) / 64.0f);
  float ang = (float)s * theta;
  float sv, cv;
  sincosf(ang, &sv, &cv);
  ct[idx] = cv;
  st[idx] = sv;
}

// X[M][1024] fp32 -> A[M][3072] bf16 triplets (hi,hi,lo)
__global__ __launch_bounds__(256) void pack_a_k(
    const float* __restrict__ X, short* __restrict__ A, int total4)
{
  int idx = blockIdx.x * 256 + threadIdx.x;
  if (idx >= total4) return;
  float4 v = ((const float4*)X)[idx];
  float a4[4] = {v.x, v.y, v.z, v.w};
  short o[12];
#pragma unroll
  for (int j = 0; j < 4; ++j) {
    short hs, ls; split_bf16(a4[j], hs, ls);
    o[3*j] = hs; o[3*j+1] = hs; o[3*j+2] = ls;
  }
  short* op = A + (size_t)idx * 12;
  *(short4*)(op)     = *(short4*)&o[0];
  *(short4*)(op + 4) = *(short4*)&o[4];
  *(short4*)(op + 8) = *(short4*)&o[8];
}

// W[K=1024][Nw] fp32 -> BT rows [n][3072] bf16 triplets (hi,lo,hi)
__global__ __launch_bounds__(256) void pack_bt_k(
    const float* __restrict__ W, short* __restrict__ BT, int Nw)
{
  __shared__ float tile[32][33];
  int kb = blockIdx.y * 32, nb = blockIdx.x * 32;
  int tx = threadIdx.x & 31, ty = threadIdx.x >> 5;
  for (int yy = ty; yy < 32; yy += 8) {
    float v = 0.f;
    if (nb + tx < Nw) v = W[(size_t)(kb + yy) * Nw + nb + tx];
    tile[yy][tx] = v;
  }
  __syncthreads();
  for (int yy = ty; yy < 32; yy += 8) {
    int n = nb + yy;
    if (n >= Nw) continue;
    int k = kb + tx;
    float f = tile[tx][yy];
    short hs, ls; split_bf16(f, hs, ls);
    short* orow = BT + (size_t)n * KP + 3 * k;
    orow[0] = hs; orow[1] = ls; orow[2] = hs;
  }
}

// Wcat[k][0:256]=Wq, [256:320]=Wk, [320:324]=Ww, [324:384]=0
__global__ __launch_bounds__(256) void pack_wcat_k(
    const float* __restrict__ Wq, const float* __restrict__ Wk,
    const float* __restrict__ Ww, float* __restrict__ Wcat)
{
  int idx = blockIdx.x * 256 + threadIdx.x;
  if (idx >= 1024 * NSTR) return;
  int k = idx / NSTR, n = idx - k * NSTR;
  float v = 0.f;
  if (n < 256)      v = Wq[(size_t)k * 256 + n];
  else if (n < 320) v = Wk[(size_t)k * 64 + (n - 256)];
  else if (n < 324) v = Ww[(size_t)k * 4 + (n - 320)];
  Wcat[idx] = v;
}

// Ccat ki slice -> kiT4[b][d4][s] (float4 of dims 4*d4..4*d4+3, contiguous in s)
__global__ __launch_bounds__(256) void tr_ki_k(
    const float* __restrict__ Ccat, float4* __restrict__ kiT4)
{
  int idx = blockIdx.x * 256 + threadIdx.x;
  if (idx >= BB * 16 * SS) return;
  int b = idx >> 15;
  int rem = idx & 32767;
  int d4 = rem >> 11;
  int s = rem & 2047;
  kiT4[idx] = *(const float4*)(Ccat + ((size_t)b * SS + s) * NSTR + 256 + 4 * d4);
}

// bf16 MFMA GEMM, split-K over blockIdx.z: partial_z[M][N] (fp16) =
// A[M][kBeg:kBeg+kLen] * BT[N][kBeg:kBeg+kLen]^T. 128x128 tile, BK=64, 4 waves.
__global__ __launch_bounds__(256) void gemm_bf16h(
    const short* __restrict__ A, const short* __restrict__ BT,
    __half* __restrict__ C, int M, int N, int Kp, int kLen)
{
  __shared__ short As[128 * 64];
  __shared__ short Bs[128 * 64];
  const int tid = threadIdx.x;
  const int lane = tid & 63;
  const int wv = tid >> 6;
  const int m0 = blockIdx.y * 128, n0 = blockIdx.x * 128;
  const int z = blockIdx.z;
  const int kBeg = z * kLen;
  __half* Cp = C + (size_t)z * M * N;
  const int wr = (wv >> 1) * 64, wc = (wv & 1) * 64;
  f32x4 acc[4][4];
#pragma unroll
  for (int i = 0; i < 4; ++i)
#pragma unroll
    for (int j = 0; j < 4; ++j)
#pragma unroll
      for (int r = 0; r < 4; ++r) acc[i][j][r] = 0.0f;

  const int rsel = lane & 15;
  const int lrow = lane >> 3;          // 0..7
  const int lcol = (lane & 7) * 8;     // shorts
  for (int k0 = kBeg; k0 < kBeg + kLen; k0 += 64) {
#pragma unroll
    for (int q = 0; q < 4; ++q) {
      int c = wv * 4 + q;              // chunk 0..15 (8 rows each)
      int row = c * 8 + lrow;
      gload16(A  + (size_t)(m0 + row) * Kp + k0 + lcol, &As[c * 512]);
      gload16(BT + (size_t)(n0 + row) * Kp + k0 + lcol, &Bs[c * 512]);
    }
    __syncthreads();
#pragma unroll
    for (int kk = 0; kk < 2; ++kk) {
      bf16x8 af[4], bfr[4];
      int kof = kk * 32 + (lane >> 4) * 8;
#pragma unroll
      for (int i = 0; i < 4; ++i) {
        af[i]  = *(const bf16x8*)&As[(wr + i * 16 + rsel) * 64 + kof];
        bfr[i] = *(const bf16x8*)&Bs[(wc + i * 16 + rsel) * 64 + kof];
      }
#pragma unroll
      for (int i = 0; i < 4; ++i)
#pragma unroll
        for (int j = 0; j < 4; ++j)
          acc[i][j] = __builtin_amdgcn_mfma_f32_16x16x32_bf16(af[i], bfr[j], acc[i][j], 0, 0, 0);
    }
    __syncthreads();
  }
  const int er = m0 + wr + (lane >> 4) * 4;
  const int ec = n0 + wc + rsel;
#pragma unroll
  for (int i = 0; i < 4; ++i)
#pragma unroll
    for (int j = 0; j < 4; ++j)
#pragma unroll
      for (int r = 0; r < 4; ++r)
        Cp[(size_t)(er + i * 16 + r) * N + ec + j * 16] = __float2half_rn(acc[i][j][r]);
}

// fp32 indexer GEMM: C[M][384] = A[M][1024] * Wcat[1024][384].
// 32x64 tile, 128 threads, 4x4/thread, grid (6,128)=768 blocks.
__global__ __launch_bounds__(128) void gemm_idx_k(
    const float* __restrict__ A, const float* __restrict__ Bw, float* __restrict__ C)
{
  __shared__ float As[16][36];
  __shared__ float Bs[16][68];
  int n0 = blockIdx.x * 64, m0 = blockIdx.y * 32;
  int tid = threadIdx.x;
  int tr = tid >> 4;        // 0..7 -> rows tr*4..+3
  int tc = tid & 15;        // 0..15 -> cols tc*4..+3
  float acc[4][4];
#pragma unroll
  for (int i = 0; i < 4; ++i)
#pragma unroll
    for (int j = 0; j < 4; ++j) acc[i][j] = 0.f;

  for (int k0 = 0; k0 < 1024; k0 += 16) {
    {
      int lin = tid * 4;
      int row = lin >> 4, kk = lin & 15;
      float4 av = *(const float4*)(A + (size_t)(m0 + row) * 1024 + k0 + kk);
      As[kk + 0][row] = av.x; As[kk + 1][row] = av.y;
      As[kk + 2][row] = av.z; As[kk + 3][row] = av.w;
      int lin2 = tid * 8;
      int bk = lin2 >> 6, bc = lin2 & 63;
      const float* bp = Bw + (size_t)(k0 + bk) * NSTR + n0 + bc;
      *(float4*)&Bs[bk][bc]     = *(const float4*)(bp);
      *(float4*)&Bs[bk][bc + 4] = *(const float4*)(bp + 4);
    }
    __syncthreads();
#pragma unroll
    for (int k = 0; k < 16; ++k) {
      float a[4], b[4];
      *(float4*)&a[0] = *(const float4*)&As[k][tr * 4];
      *(float4*)&b[0] = *(const float4*)&Bs[k][tc * 4];
#pragma unroll
      for (int i = 0; i < 4; ++i)
#pragma unroll
        for (int j = 0; j < 4; ++j)
          acc[i][j] = fmaf(a[i], b[j], acc[i][j]);
    }
    __syncthreads();
  }
#pragma unroll
  for (int i = 0; i < 4; ++i)
    *(float4*)(C + (size_t)(m0 + tr * 4 + i) * NSTR + n0 + tc * 4) = *(float4*)&acc[i][0];
}

// P (2 fp16 partials, stride ROWS*3072) -> sum -> RoPE(q,k) + fp16; Q pre-scaled 1/8.
__global__ __launch_bounds__(256) void qkv_post_k(
    const __half* __restrict__ P, const float* __restrict__ ct, const float* __restrict__ st,
    __half* __restrict__ Qh, __half* __restrict__ Kh, __half* __restrict__ Vh)
{
  int idx = blockIdx.x * 256 + threadIdx.x;
  if (idx >= ROWS * 384) return;
  int m = idx / 384;
  int g = idx - m * 384;
  int col0 = g * 8;
  const __half* c0 = P + (size_t)m * 3072 + col0;
  const __half* c1 = c0 + (size_t)ROWS * 3072;
  float4 u = *(const float4*)c0;
  float4 v = *(const float4*)c1;
  const __half2* hu = (const __half2*)&u;
  const __half2* hv = (const __half2*)&v;
  float a[8];
#pragma unroll
  for (int c = 0; c < 4; ++c) {
    float2 x = __half22float2(hu[c]);
    float2 y = __half22float2(hv[c]);
    a[2*c]   = x.x + y.x;
    a[2*c+1] = x.y + y.y;
  }
  int sec = col0 >> 10;
  int cin = col0 & 1023;
  size_t orow = (size_t)m * 1024 + cin;
  if (sec == 2) {
    __half2 hh[4];
#pragma unroll
    for (int c = 0; c < 4; ++c) hh[c] = __floats2half2_rn(a[2*c], a[2*c+1]);
    *(float4*)(Vh + orow) = *(float4*)hh;
  } else {
    int t = m & (SS - 1);
    int jb = (cin & 63) >> 1;
    float o[8];
#pragma unroll
    for (int c = 0; c < 4; ++c) {
      float cv = ct[t * 32 + jb + c], sv = st[t * 32 + jb + c];
      float x1 = a[2*c], x2 = a[2*c+1];
      o[2*c]   = x1 * cv - x2 * sv;
      o[2*c+1] = x2 * cv + x1 * sv;
    }
    if (sec == 0) {
#pragma unroll
      for (int c = 0; c < 8; ++c) o[c] *= 0.125f;   // fold 1/sqrt(64)
    }
    __half2 hh[4];
#pragma unroll
    for (int c = 0; c < 4; ++c) hh[c] = __floats2half2_rn(o[2*c], o[2*c+1]);
    __half* dst = (sec == 0) ? Qh : Kh;
    *(float4*)(dst + orow) = *(float4*)hh;
  }
}

// Vh (b,s,h*64+d) -> VhT [(b*16+h)*64+d][s]
__global__ __launch_bounds__(256) void vt_k(
    const __half* __restrict__ Vh, __half* __restrict__ VhT)
{
  int st = blockIdx.x, bh = blockIdx.y;
  int b = bh >> 4, h = bh & 15;
  int s0 = st * 64;
  __shared__ __half tile[64][65];
  int tid = threadIdx.x;
#pragma unroll
  for (int rnd = 0; rnd < 2; ++rnd) {
    int row = (tid >> 3) + rnd * 32;
    int c8 = (tid & 7) * 8;
    *(float4*)&tile[row][c8] =
        *(const float4*)(Vh + ((size_t)b * SS + s0 + row) * 1024 + h * 64 + c8);
  }
  __syncthreads();
#pragma unroll
  for (int rnd = 0; rnd < 2; ++rnd) {
    int d = (tid >> 3) + rnd * 32;
    int s8 = (tid & 7) * 8;
    __half tmp[8];
#pragma unroll
    for (int j = 0; j < 8; ++j) tmp[j] = tile[s8 + j][d];
    *(float4*)(VhT + ((size_t)bh * 64 + d) * 2048 + s0 + s8) = *(float4*)tmp;
  }
}

// Per (b,t): indexer scores for s<=t (fp32, per-output chain identical to prior
// rounds; ki read from transposed kiT4 -> coalesced), exact top-512 radix select
// (stable lowest-index ties), 2048-bit mask. LPT mapping.
__global__ __launch_bounds__(256) void idx_topk_k(
    const float* __restrict__ Ccat, const float4* __restrict__ kiT4,
    u32* __restrict__ msk)
{
  int b = blockIdx.y;
  int t = SS - 1 - blockIdx.x;      // LPT: longest blocks dispatch first
  int tid = threadIdx.x;
  int lane = tid & 63;
  int wv = tid >> 6;
  if (t < TOPK) {  // -1e9 ties => selection is exactly [0..511]
    if (tid < 64)
      msk[((size_t)b * SS + t) * 64 + tid] = (tid < 16) ? 0xFFFFFFFFu : 0u;
    return;
  }
  __shared__ u32 uk[SS];        // 8KB monotonic keys
  __shared__ u32 hist[256];
  __shared__ u32 w[64];
  __shared__ u32 s_bsel, s_above;

  if (tid < 64) w[tid] = 0u;

  const float4* qrow = (const float4*)(Ccat + ((size_t)b * SS + t) * NSTR);
  const float* wrow = Ccat + ((size_t)b * SS + t) * NSTR + 320;
  float w0 = wrow[0], w1 = wrow[1], w2 = wrow[2], w3 = wrow[3];
  const float4* kb = kiT4 + (size_t)b * 16 * SS;   // [16][2048] float4

  // ---- scores -> keys (chain identical; ki loads coalesced via kiT4) ----
#pragma unroll 1
  for (int s0 = 0; s0 <= t; s0 += 256) {
    int s = s0 + tid;
    if (s <= t) {
      float a0 = 0.f, a1 = 0.f, a2 = 0.f, a3 = 0.f;
#pragma unroll
      for (int d4 = 0; d4 < 16; ++d4) {
        float4 kv = kb[d4 * SS + s];
        float4 q0 = qrow[d4];
        float4 q1 = qrow[16 + d4];
        float4 q2 = qrow[32 + d4];
        float4 q3 = qrow[48 + d4];
        a0 += q0.x * kv.x + q0.y * kv.y + q0.z * kv.z + q0.w * kv.w;
        a1 += q1.x * kv.x + q1.y * kv.y + q1.z * kv.z + q1.w * kv.w;
        a2 += q2.x * kv.x + q2.y * kv.y + q2.z * kv.z + q2.w * kv.w;
        a3 += q3.x * kv.x + q3.y * kv.y + q3.z * kv.z + q3.w * kv.w;
      }
      float v = fmaxf(a0, 0.f) * w0 + fmaxf(a1, 0.f) * w1 +
                fmaxf(a2, 0.f) * w2 + fmaxf(a3, 0.f) * w3;
      uk[s] = fkey(v);
    }
  }

  // ---- 4-pass radix: threshold key ----
  unsigned krem = TOPK;
  unsigned prefix = 0;
#pragma unroll 1
  for (int p = 0; p < 4; ++p) {
    int shift = 24 - 8 * p;
    u32 maskAbove = (p == 0) ? 0u : (0xFFFFFFFFu << (shift + 8));
    hist[tid] = 0u;
    __syncthreads();
#pragma unroll 1
    for (int s0 = 0; s0 <= t; s0 += 256) {
      int s = s0 + tid;
      if (s <= t) {
        u32 key = uk[s];
        if ((key & maskAbove) == prefix)
          atomicAdd(&hist[(key >> shift) & 255], 1u);
      }
    }
    __syncthreads();
    // wave-0 suffix scan of 256 bins (4 bins/lane), no inner barriers
    if (wv == 0) {
      uint4 hv = *(uint4*)&hist[lane * 4];
      u32 lsum = hv.x + hv.y + hv.z + hv.w;
      u32 x = lsum;
#pragma unroll
      for (int off = 1; off < 64; off <<= 1) {
        u32 y = __shfl_down(x, off);
        x += (lane + off < 64) ? y : 0u;
      }
      u32 esuf = x - lsum;            // suffix over lanes > L
      u32 S3 = esuf + hv.w;
      u32 S2 = S3 + hv.z;
      u32 S1 = S2 + hv.y;
      u32 S0 = S1 + hv.x;
      if (S0 >= krem && S1 < krem)  { s_bsel = lane * 4 + 0; s_above = S1; }
      if (S1 >= krem && S2 < krem)  { s_bsel = lane * 4 + 1; s_above = S2; }
      if (S2 >= krem && S3 < krem)  { s_bsel = lane * 4 + 2; s_above = S3; }
      if (S3 >= krem && esuf < krem){ s_bsel = lane * 4 + 3; s_above = esuf; }
    }
    __syncthreads();
    prefix |= (s_bsel << shift);
    krem -= s_above;
  }

  u32 Tkey = prefix;
  unsigned kfin = krem;               // # of ==Tkey to take (lowest indices)

  // ---- collect > Tkey: ballot word-OR straight into the bitmask ----
#pragma unroll 1
  for (int s0 = 0; s0 <= t; s0 += 256) {
    int s = s0 + tid;
    bool pred = (s <= t) && (uk[s] > Tkey);
    unsigned long long mba = __ballot(pred);
    int wbase = (s0 + wv * 64) >> 5;
    if (lane == 0 && (u32)mba) atomicOr(&w[wbase], (u32)mba);
    if (lane == 32 && (u32)(mba >> 32)) atomicOr(&w[wbase + 1], (u32)(mba >> 32));
  }
  // ---- collect == Tkey, lowest-index-first (wave 0) ----
  if (wv == 0) {
    unsigned taken = 0;
#pragma unroll 1
    for (int s0 = 0; s0 <= t && taken < kfin; s0 += 64) {
      int s = s0 + lane;
      bool pred = (s <= t) && (uk[s] == Tkey);
      unsigned long long mba = __ballot(pred);
      unsigned pre = (unsigned)__popcll(mba & ((1ull << lane) - 1ull));
      if (pred && (taken + pre) < kfin)
        atomicOr(&w[s >> 5], 1u << (s & 31));
      taken += (unsigned)__popcll(mba);
    }
  }
  __syncthreads();
  if (tid < 64) msk[((size_t)b * SS + t) * 64 + tid] = w[tid];
}

// Dense masked flash attention, f16 MFMA. Block = (b,h, 64-query tile).
// Key-tile bound: selection for row t is within [0..max(t,511)], so tiles
// kt > max(qt,7) are fully masked -> bit-exact no-ops and are skipped.
// LPT: longest query tiles dispatch first.
// Emits split-bf16 triplets (hi,hi,lo) directly into Aattn for the out-proj GEMM.
__global__ __launch_bounds__(256) void attn_dense_k(
    const __half* __restrict__ Qh, const __half* __restrict__ Kh,
    const __half* __restrict__ VhT, const u32* __restrict__ msk,
    short* __restrict__ Aattn)
{
  int bid = blockIdx.x;
  int xcd = bid & 7, loc = bid >> 3;
  int bh = xcd * 4 + (loc >> 5);       // 4 (b,h) pairs per XCD -> K/V L2-resident
  int qt = 31 - (loc & 31);            // LPT: qt=31 (32 key tiles) first
  int b = bh >> 4, h = bh & 15;
  int t0 = qt * 64;
  const int ktEnd = (qt < 8) ? 7 : qt; // t<512 rows select keys up to s=511

  const int tid = threadIdx.x;
  const int lane = tid & 63;
  const int wv = tid >> 6;
  const int l15 = lane & 15;
  const int g = lane >> 4;

  __shared__ short lds[12800];          // Ks 4096 | Vt 4096 | Ps 4*1088 | mask 256
  short* Ks = lds;                      // [64 keys][8 chunks] XOR-swizzled
  short* Vt = lds + 4096;               // [64 dims][8 chunks] XOR-swizzled
  short* Ps = lds + 8192 + wv * 1088;   // per-wave [16 queries][68]
  u32* mlds = (u32*)(lds + 12544);      // [64 queries][2 words]

  const size_t brow = (size_t)b * SS;

  // Q A-fragments (m = this wave's 16 queries), resident in regs
  f16x8 qf0, qf1;
  {
    const __half* qp = Qh + (brow + t0 + wv * 16 + l15) * 1024 + h * 64 + g * 8;
    qf0 = *(const f16x8*)(qp);
    qf1 = *(const f16x8*)(qp + 32);
  }

  f32x4 accO[4];
#pragma unroll
  for (int n2 = 0; n2 < 4; ++n2)
#pragma unroll
    for (int r = 0; r < 4; ++r) accO[n2][r] = 0.f;
  float mRun[4] = {-1e30f, -1e30f, -1e30f, -1e30f};
  float sRun[4] = {0.f, 0.f, 0.f, 0.f};

  const int srow = lane >> 3;           // staging row within 8-row group
  const int scp  = (lane & 7) ^ srow;   // pre-swizzled source chunk

#pragma unroll 1
  for (int kt = 0; kt <= ktEnd; ++kt) { // kt > ktEnd is a bit-exact no-op
    int kt0 = kt * 64;
    // ---- stage K tile, V^T tile (DMA, linear dest + inverse-swizzled src), mask ----
#pragma unroll
    for (int q = 0; q < 2; ++q) {
      int j = wv * 2 + q;
      gload16(Kh + (brow + kt0 + j * 8 + srow) * 1024 + h * 64 + scp * 8, Ks + j * 512);
      gload16(VhT + ((size_t)(bh * 64 + j * 8 + srow)) * 2048 + kt0 + scp * 8, Vt + j * 512);
    }
    if (tid < 128)
      mlds[tid] = msk[(brow + t0 + (tid >> 1)) * 64 + kt * 2 + (tid & 1)];
    __syncthreads();

    // ---- QK^T: D[m=query][n=key] ----
    f32x4 s4[4];
#pragma unroll
    for (int ns = 0; ns < 4; ++ns) {
#pragma unroll
      for (int r = 0; r < 4; ++r) s4[ns][r] = 0.f;
      int rowk = ns * 16 + l15;
      int cp0 = g ^ (rowk & 7);
      int cp1 = (4 + g) ^ (rowk & 7);
      f16x8 kf0 = *(const f16x8*)&Ks[rowk * 64 + cp0 * 8];
      f16x8 kf1 = *(const f16x8*)&Ks[rowk * 64 + cp1 * 8];
      s4[ns] = __builtin_amdgcn_mfma_f32_16x16x32_f16(qf0, kf0, s4[ns], 0, 0, 0);
      s4[ns] = __builtin_amdgcn_mfma_f32_16x16x32_f16(qf1, kf1, s4[ns], 0, 0, 0);
    }

    // ---- masked online softmax (per query row r; keys across l15 x ns) ----
#pragma unroll
    for (int r = 0; r < 4; ++r) {
      int qb2 = (wv * 16 + g * 4 + r) * 2;
      u32 w0 = mlds[qb2];
      u32 w1 = mlds[qb2 + 1];
      float le[4];
#pragma unroll
      for (int ns = 0; ns < 4; ++ns) {
        u32 w = (ns < 2) ? w0 : w1;
        int bit = (ns & 1) * 16 + l15;
        float l = s4[ns][r];
        le[ns] = ((w >> bit) & 1u) ? l : -1e30f;
      }
      float cm = fmaxf(fmaxf(le[0], le[1]), fmaxf(le[2], le[3]));
      cm = fmaxf(cm, __shfl_xor(cm, 1));
      cm = fmaxf(cm, __shfl_xor(cm, 2));
      cm = fmaxf(cm, __shfl_xor(cm, 4));
      cm = fmaxf(cm, __shfl_xor(cm, 8));
      float mn = fmaxf(mRun[r], cm);
      float fac = __expf(mRun[r] - mn);
      mRun[r] = mn;
      float sum = 0.f;
#pragma unroll
      for (int ns = 0; ns < 4; ++ns) {
        float ee = __expf(le[ns] - mn);
        ee = (le[ns] < -1e29f) ? 0.f : ee;   // masked -> exactly 0
        sum += ee;
        Ps[(g * 4 + r) * 68 + ns * 16 + l15] =
            (short)__half_as_ushort(__float2half_rn(ee));
      }
      sum += __shfl_xor(sum, 1);
      sum += __shfl_xor(sum, 2);
      sum += __shfl_xor(sum, 4);
      sum += __shfl_xor(sum, 8);
      sRun[r] = sRun[r] * fac + sum;
#pragma unroll
      for (int n2 = 0; n2 < 4; ++n2) accO[n2][r] *= fac;
    }

    // ---- PV: D[m=query][n=dim] += P * V ----
    f16x8 pa0, pa1;
    {
      const short* pp = &Ps[l15 * 68 + g * 8];
      float2 lo0 = *(const float2*)(pp);
      float2 hi0 = *(const float2*)(pp + 4);
      float2 lo1 = *(const float2*)(pp + 32);
      float2 hi1 = *(const float2*)(pp + 36);
      float4 c0 = make_float4(lo0.x, lo0.y, hi0.x, hi0.y);
      float4 c1 = make_float4(lo1.x, lo1.y, hi1.x, hi1.y);
      pa0 = *(const f16x8*)&c0;
      pa1 = *(const f16x8*)&c1;
    }
#pragma unroll
    for (int n2 = 0; n2 < 4; ++n2) {
      int rowd = n2 * 16 + l15;
      int cp0 = g ^ (rowd & 7);
      int cp1 = (4 + g) ^ (rowd & 7);
      f16x8 vf0 = *(const f16x8*)&Vt[rowd * 64 + cp0 * 8];
      f16x8 vf1 = *(const f16x8*)&Vt[rowd * 64 + cp1 * 8];
      accO[n2] = __builtin_amdgcn_mfma_f32_16x16x32_f16(pa0, vf0, accO[n2], 0, 0, 0);
      accO[n2] = __builtin_amdgcn_mfma_f32_16x16x32_f16(pa1, vf1, accO[n2], 0, 0, 0);
    }
    __syncthreads();
  }

#pragma unroll
  for (int r = 0; r < 4; ++r) {
    float inv = 1.0f / sRun[r];
    size_t grow = brow + t0 + wv * 16 + g * 4 + r;
    short* arow = Aattn + grow * 3072;
#pragma unroll
    for (int n2 = 0; n2 < 4; ++n2) {
      int col = h * 64 + n2 * 16 + l15;
      float v = accO[n2][r] * inv;
      short hs, ls; split_bf16(v, hs, ls);
      short* ap = arow + 3 * col;
      ap[0] = hs; ap[1] = hs; ap[2] = ls;
    }
  }
}

// out = sum of 3 fp16 out-proj partials (stride ROWS*1024)
__global__ __launch_bounds__(256) void redout_k(
    const __half* __restrict__ O, float* __restrict__ out)
{
  int idx = blockIdx.x * 256 + threadIdx.x;   // 8 elems/thread
  if (idx >= ROWS * 1024 / 8) return;
  const size_t PS = (size_t)ROWS * 1024;
  float4 u0 = *((const float4*)O + idx);
  float4 u1 = *((const float4*)(O + PS) + idx);
  float4 u2 = *((const float4*)(O + 2 * PS) + idx);
  const __half2* h0 = (const __half2*)&u0;
  const __half2* h1 = (const __half2*)&u1;
  const __half2* h2 = (const __half2*)&u2;
  float o[8];
#pragma unroll
  for (int c = 0; c < 4; ++c) {
    float2 a = __half22float2(h0[c]);
    float2 b = __half22float2(h1[c]);
    float2 d = __half22float2(h2[c]);
    o[2*c]   = a.x + b.x + d.x;
    o[2*c+1] = a.y + b.y + d.y;
  }
  float* op = out + (size_t)idx * 8;
  *(float4*)(op)     = make_float4(o[0], o[1], o[2], o[3]);
  *(float4*)(op + 4) = make_float4(o[4], o[5], o[6], o[7]);
}

extern "C" void kernel_launch(void* const* d_in, const int* in_sizes, int n_in,
                              void* d_out, int out_size, void* d_ws, size_t ws_size,
                              hipStream_t stream) {
  const float* x    = (const float*)d_in[0];
  const float* Wqkv = (const float*)d_in[1];
  const float* Wo   = (const float*)d_in[2];
  const float* Wq   = (const float*)d_in[3];
  const float* Wk   = (const float*)d_in[4];
  const float* Ww   = (const float*)d_in[5];
  float* out = (float*)d_out;

  float* fws = (float*)d_ws;
  size_t o = 0;
  __half* Qh    = (__half*)(fws + o);  o += (size_t)ROWS * 512;
  __half* Kh    = (__half*)(fws + o);  o += (size_t)ROWS * 512;
  __half* Vh    = (__half*)(fws + o);  o += (size_t)ROWS * 512;
  float*  ct    = fws + o;             o += (size_t)SS * 32;
  float*  st    = fws + o;             o += (size_t)SS * 32;
  float*  Ccat  = fws + o;             o += (size_t)ROWS * NSTR;       // fused qi|ki|w (padded)
  short*  BTwo  = (short*)(fws + o);   o += (size_t)1024 * KP / 2;
  short*  BTq   = (short*)(fws + o);   o += (size_t)3072 * KP / 2;
  short*  Ax    = (short*)(fws + o);                                   // aliased (ROWS*KP shorts):
  float*  Wcat  = fws + o + (size_t)ROWS * 1024;                       //  Wcat in dead tail of Ax
  /* region size */                    o += (size_t)ROWS * KP / 2;
  // Cbuf region (ROWS*3072 floats), time-multiplexed:
  //   phase 1: Ph = 2 fp16 qkv partials (whole region)
  //   phase 2: Aattn [0,6.3M fl) | VhT +8M fl | msk +10.5M fl | kiT4 +11M fl
  __half* Ph    = (__half*)(fws + o);
  short*  Aattn = (short*)(fws + o);
  __half* VhT   = (__half*)(fws + o + (size_t)8 * 1024 * 1024);
  u32*    msk   = (u32*)(fws + o + (size_t)10500 * 1024);
  float4* kiT4  = (float4*)(fws + o + (size_t)11264 * 1024);
  o += (size_t)ROWS * 3072;
  // out-proj partials: 3 x ROWS*1024 halves == Qh+Kh+Vh region (dead by then)
  __half* Oparts = (__half*)Qh;

  rope_tab_k<<<dim3((SS * 32 + 255) / 256), dim3(256), 0, stream>>>(ct, st);

  // packs for the two MFMA GEMMs
  pack_a_k<<<dim3(ROWS * KDIM / 4 / 256), dim3(256), 0, stream>>>(x, Ax, ROWS * KDIM / 4);
  pack_bt_k<<<dim3(3072 / 32, 32), dim3(256), 0, stream>>>(Wqkv, BTq, 3072);
  pack_bt_k<<<dim3(1024 / 32, 32), dim3(256), 0, stream>>>(Wo, BTwo, 1024);

  // qkv GEMM (split-bf16 MFMA, split-K x2 -> fp16 partials)
  gemm_bf16h<<<dim3(3072 / 128, ROWS / 128, 2), dim3(256), 0, stream>>>(
      Ax, BTq, Ph, ROWS, 3072, KP, KP / 2);
  qkv_post_k<<<dim3((ROWS * 384 + 255) / 256), dim3(256), 0, stream>>>(Ph, ct, st, Qh, Kh, Vh);
  vt_k<<<dim3(SS / 64, BB * HH), dim3(256), 0, stream>>>(Vh, VhT);

  // fused indexer projections in fp32 (bit-identical chain; feeds exact top-k)
  pack_wcat_k<<<dim3((1024 * NSTR + 255) / 256), dim3(256), 0, stream>>>(Wq, Wk, Ww, Wcat);
  gemm_idx_k<<<dim3(NSTR / 64, ROWS / 32), dim3(128), 0, stream>>>(x, Wcat, Ccat);
  tr_ki_k<<<dim3(BB * 16 * SS / 256), dim3(256), 0, stream>>>(Ccat, kiT4);

  idx_topk_k<<<dim3(SS, BB), dim3(256), 0, stream>>>(Ccat, kiT4, msk);
  attn_dense_k<<<dim3(1024), dim3(256), 0, stream>>>(Qh, Kh, VhT, msk, Aattn);

  // out = attn @ Wo (split-bf16 MFMA, split-K x3 -> fp16 partials in dead Qh/Kh/Vh)
  gemm_bf16h<<<dim3(1024 / 128, ROWS / 128, 3), dim3(256), 0, stream>>>(
      Aattn, BTwo, Oparts, ROWS, 1024, KP, KP / 3);
  redout_k<<<dim3(ROWS * 1024 / 8 / 256), dim3(256), 0, stream>>>(Oparts, out);
}